// Round 1
// baseline (714.212 us; speedup 1.0000x reference)
//
#include <hip/hip_runtime.h>
#include <stdint.h>

#define BB 256
#define VV 128000
#define NT 1024
#define NBUCK 4096
#define CAP 4096

__device__ __forceinline__ uint32_t rotl32(uint32_t v, uint32_t r) {
    return (v << r) | (v >> (32u - r));
}

// JAX partitionable threefry, 32-bit draw at flat index j (< 2^32):
// key = (0,1)  [jax.random.key(1)], counter = (hi=0, lo=j), bits = o0 ^ o1.
__device__ __forceinline__ uint32_t threefry_bits(uint32_t j) {
    const uint32_t ks0 = 0u, ks1 = 1u, ks2 = 0x1BD11BDBu; // 0^1^0x1BD11BDA
    uint32_t x0 = ks0;      // ctr_hi(0) + ks0
    uint32_t x1 = j + ks1;  // ctr_lo(j) + ks1
    // round group 0 (R0 = 13,15,26,6)
    x0 += x1; x1 = rotl32(x1, 13); x1 ^= x0;
    x0 += x1; x1 = rotl32(x1, 15); x1 ^= x0;
    x0 += x1; x1 = rotl32(x1, 26); x1 ^= x0;
    x0 += x1; x1 = rotl32(x1, 6);  x1 ^= x0;
    x0 += ks1; x1 += ks2 + 1u;
    // group 1 (R1 = 17,29,16,24)
    x0 += x1; x1 = rotl32(x1, 17); x1 ^= x0;
    x0 += x1; x1 = rotl32(x1, 29); x1 ^= x0;
    x0 += x1; x1 = rotl32(x1, 16); x1 ^= x0;
    x0 += x1; x1 = rotl32(x1, 24); x1 ^= x0;
    x0 += ks2; x1 += ks0 + 2u;
    // group 2 (R0)
    x0 += x1; x1 = rotl32(x1, 13); x1 ^= x0;
    x0 += x1; x1 = rotl32(x1, 15); x1 ^= x0;
    x0 += x1; x1 = rotl32(x1, 26); x1 ^= x0;
    x0 += x1; x1 = rotl32(x1, 6);  x1 ^= x0;
    x0 += ks0; x1 += ks1 + 3u;
    // group 3 (R1)
    x0 += x1; x1 = rotl32(x1, 17); x1 ^= x0;
    x0 += x1; x1 = rotl32(x1, 29); x1 ^= x0;
    x0 += x1; x1 = rotl32(x1, 16); x1 ^= x0;
    x0 += x1; x1 = rotl32(x1, 24); x1 ^= x0;
    x0 += ks1; x1 += ks2 + 4u;
    // group 4 (R0)
    x0 += x1; x1 = rotl32(x1, 13); x1 ^= x0;
    x0 += x1; x1 = rotl32(x1, 15); x1 ^= x0;
    x0 += x1; x1 = rotl32(x1, 26); x1 ^= x0;
    x0 += x1; x1 = rotl32(x1, 6);  x1 ^= x0;
    x0 += ks2; x1 += ks0 + 5u;
    return x0 ^ x1;
}

// p must be computed with identical ops in every pass (deterministic IEEE fp32).
__device__ __forceinline__ float prob_of(float logit, float T, float xm, float Zf) {
    float x = logit / T;
    return expf(x - xm) / Zf;
}

extern "C" __global__ void __launch_bounds__(NT, 1)
sampler_kernel(const float* __restrict__ logits,
               const float* __restrict__ temps,
               const float* __restrict__ topps,
               int* __restrict__ out) {
    const int row = blockIdx.x;
    const int tid = threadIdx.x;
    const float* L = logits + (size_t)row * VV;

    // 60KB phase-aliased LDS union
    __shared__ __align__(16) unsigned char SMEM[61440];
    double* hist = (double*)SMEM;                         // P3:  [0, 32768)
    unsigned* hcnt = (unsigned*)(SMEM + 32768);           // P3:  [32768, 49152)
    double* csum = (double*)(SMEM + 49152);               // P3c: [49152, 57344)
    unsigned* ccnt = (unsigned*)(SMEM + 57344);           // P3c: [57344, 61440)
    unsigned long long* sortbuf = (unsigned long long*)SMEM; // P4: [0, 32768)
    float* rf = (float*)SMEM;                             // P1/P5: [0, 4096)
    int* ri = (int*)(SMEM + 4096);                        // P1/P5: [4096, 8192)
    double* rd = (double*)SMEM;                           // P2:  [0, 8192)

    __shared__ float sh_T, sh_tp, sh_xm, sh_Zf;
    __shared__ int sh_gidx, sh_bstar, sh_cabove, sh_ng;
    __shared__ double sh_M;
    __shared__ unsigned long long sh_keycut;

    if (tid == 0) {
        sh_T = fmaxf(temps[row], 1e-5f);
        sh_tp = topps[row];
    }
    __syncthreads();
    const float T = sh_T;
    const float tp = sh_tp;

    // ---- P1: max + argmax(logits) (first-index tie-break) ----
    float lm = -3.4e38f; int li = 0;
    for (int v = tid; v < VV; v += NT) {
        float x = L[v];
        if (x > lm) { lm = x; li = v; }
    }
    rf[tid] = lm; ri[tid] = li;
    __syncthreads();
    for (int s = NT / 2; s > 0; s >>= 1) {
        if (tid < s) {
            float a = rf[tid], b = rf[tid + s];
            int ia = ri[tid], ib = ri[tid + s];
            if (b > a || (b == a && ib < ia)) { rf[tid] = b; ri[tid] = ib; }
        }
        __syncthreads();
    }
    if (tid == 0) { sh_gidx = ri[0]; sh_xm = rf[0] / T; }
    __syncthreads();
    const float xm = sh_xm;
    const int gidx = sh_gidx;

    // ---- P2: Z = sum exp(l/T - m/T), fp64 accumulate ----
    double lz = 0.0;
    for (int v = tid; v < VV; v += NT) {
        float x = L[v] / T;
        lz += (double)expf(x - xm);
    }
    __syncthreads(); // rf/ri -> rd alias switch
    rd[tid] = lz;
    __syncthreads();
    for (int s = NT / 2; s > 0; s >>= 1) {
        if (tid < s) rd[tid] += rd[tid + s];
        __syncthreads();
    }
    if (tid == 0) sh_Zf = (float)rd[0];
    __syncthreads();
    const float Zf = sh_Zf;

    // ---- P3: histogram of p by float-bit bucket (monotone in p) ----
    __syncthreads();
    for (int i = tid; i < NBUCK; i += NT) { hist[i] = 0.0; hcnt[i] = 0u; }
    __syncthreads();
    for (int v = tid; v < VV; v += NT) {
        float p = prob_of(L[v], T, xm, Zf);
        unsigned pb = __float_as_uint(p);
        int b = (int)(pb >> 18);
        atomicAdd(&hist[b], (double)p);
        atomicAdd(&hcnt[b], 1u);
    }
    __syncthreads();
    // chunk partials: 1024 chunks x 4 buckets
    {
        int t = tid;
        csum[t] = hist[4 * t] + hist[4 * t + 1] + hist[4 * t + 2] + hist[4 * t + 3];
        ccnt[t] = hcnt[4 * t] + hcnt[4 * t + 1] + hcnt[4 * t + 2] + hcnt[4 * t + 3];
    }
    __syncthreads();
    // P3c: descending scan to find crossing bucket b*, mass above M, count above
    if (tid == 0) {
        double c = 0.0; long long ca = 0; int bst = -1; double M = 0.0;
        for (int t = 1023; t >= 0; t--) {
            double cs_ = csum[t];
            if (c + cs_ > (double)tp) {
                bool found = false;
                for (int b = 4 * t + 3; b >= 4 * t; b--) {
                    double bs_ = hist[b];
                    if (c + bs_ > (double)tp) { bst = b; M = c; found = true; break; }
                    c += bs_; ca += (long long)hcnt[b];
                }
                if (found) break;
                // fp64 grouping edge: fell through -> keep scanning lower chunks
            } else {
                c += cs_; ca += (long long)ccnt[t];
            }
        }
        sh_bstar = bst; sh_M = M; sh_cabove = (int)ca;
        sh_ng = 0; sh_keycut = 0ULL;
    }
    __syncthreads();
    const int bstar = sh_bstar;

    // ---- P4: gather crossing bucket, bitonic sort desc by (p, ~idx), exact cut ----
    if (bstar >= 0) {
        for (int v = tid; v < VV; v += NT) {
            float p = prob_of(L[v], T, xm, Zf);
            unsigned pb = __float_as_uint(p);
            if ((int)(pb >> 18) == bstar) {
                int pos = atomicAdd(&sh_ng, 1);
                if (pos < CAP)
                    sortbuf[pos] = ((unsigned long long)pb << 32) | (unsigned)(~(unsigned)v);
            }
        }
        __syncthreads();
        int n = sh_ng; if (n > CAP) n = CAP; // overflow ~impossible (est. max ~1100)
        int npad = 1; while (npad < n) npad <<= 1; if (npad < 2) npad = 2;
        for (int i = tid; i < npad; i += NT) if (i >= n) sortbuf[i] = 0ULL;
        __syncthreads();
        for (int k = 2; k <= npad; k <<= 1) {
            for (int jj = k >> 1; jj > 0; jj >>= 1) {
                for (int i = tid; i < npad; i += NT) {
                    int prt = i ^ jj;
                    if (prt > i) {
                        unsigned long long a = sortbuf[i], b2 = sortbuf[prt];
                        bool desc = ((i & k) == 0);
                        if (desc ? (a < b2) : (a > b2)) { sortbuf[i] = b2; sortbuf[prt] = a; }
                    }
                }
                __syncthreads();
            }
        }
        if (tid == 0) {
            double c = sh_M; int jstar = 0;
            for (int i2 = 0; i2 < n; i2++) {
                float p = __uint_as_float((unsigned)(sortbuf[i2] >> 32));
                if (c + (double)p > (double)tp) break; // inclusive cum > top_p -> masked
                c += (double)p; jstar = i2 + 1;
            }
            // mask[:,0] = False: rank-0 element always kept
            if (jstar == 0 && sh_cabove == 0) jstar = 1;
            sh_keycut = (jstar > 0) ? sortbuf[jstar - 1] : 0xFFFFFFFFFFFFFFFFULL;
        }
        __syncthreads();
    }
    const unsigned long long keycut = sh_keycut;

    // ---- P5: argmax over kept of p/noise (threefry noise), first-index ties ----
    __syncthreads(); // sortbuf -> rf/ri alias switch
    float bs = -1.0f; int bi = 0x7FFFFFFF;
    const uint32_t jbase = (uint32_t)(row * VV);
    for (int v = tid; v < VV; v += NT) {
        float p = prob_of(L[v], T, xm, Zf);
        unsigned pb = __float_as_uint(p);
        int b = (int)(pb >> 18);
        unsigned long long key = ((unsigned long long)pb << 32) | (unsigned)(~(unsigned)v);
        bool kept = (b > bstar) || ((b == bstar) && (key >= keycut));
        if (__ballot(kept) != 0ULL) { // wave-uniform skip of threefry when nothing kept
            if (kept) {
                uint32_t bits = threefry_bits(jbase + (uint32_t)v);
                float u = __uint_as_float((bits >> 9) | 0x3F800000u) - 1.0f;
                float nz = -log1pf(-u);
                nz = fmaxf(nz, 1e-10f);
                float sc = p / nz;
                if (sc > bs || (sc == bs && v < bi)) { bs = sc; bi = v; }
            }
        }
    }
    rf[tid] = bs; ri[tid] = bi;
    __syncthreads();
    for (int s = NT / 2; s > 0; s >>= 1) {
        if (tid < s) {
            float a = rf[tid], b2 = rf[tid + s];
            int ia = ri[tid], ib = ri[tid + s];
            if (b2 > a || (b2 == a && ib < ia)) { rf[tid] = b2; ri[tid] = ib; }
        }
        __syncthreads();
    }
    if (tid == 0) {
        out[row] = (temps[row] <= 1e-10f) ? gidx : ri[0];
    }
}

extern "C" void kernel_launch(void* const* d_in, const int* in_sizes, int n_in,
                              void* d_out, int out_size, void* d_ws, size_t ws_size,
                              hipStream_t stream) {
    const float* logits = (const float*)d_in[0];
    const float* temps = (const float*)d_in[1];
    const float* topps = (const float*)d_in[2];
    int* out = (int*)d_out;
    (void)in_sizes; (void)n_in; (void)out_size; (void)d_ws; (void)ws_size;
    sampler_kernel<<<dim3(BB), dim3(NT), 0, stream>>>(logits, temps, topps, out);
}

// Round 2
// 576.572 us; speedup vs baseline: 1.2387x; 1.2387x over previous
//
#include <hip/hip_runtime.h>
#include <stdint.h>

#define BB 256
#define VV 128000
#define NV4 (VV / 4)      // 32000 float4 per row
#define NT 1024
#define NWAVE (NT / 64)
#define NBUCK 4096
#define CAP 4096

__device__ __forceinline__ uint32_t rotl32(uint32_t v, uint32_t r) {
    return (v << r) | (v >> (32u - r));
}

// JAX partitionable threefry, 32-bit draw at flat index j (< 2^32):
// key = (0,1)  [jax.random.key(1)], counter = (hi=0, lo=j), bits = o0 ^ o1.
// Verified bit-exact in round 1 (absmax 0). DO NOT TOUCH.
__device__ __forceinline__ uint32_t threefry_bits(uint32_t j) {
    const uint32_t ks0 = 0u, ks1 = 1u, ks2 = 0x1BD11BDBu;
    uint32_t x0 = ks0;
    uint32_t x1 = j + ks1;
    x0 += x1; x1 = rotl32(x1, 13); x1 ^= x0;
    x0 += x1; x1 = rotl32(x1, 15); x1 ^= x0;
    x0 += x1; x1 = rotl32(x1, 26); x1 ^= x0;
    x0 += x1; x1 = rotl32(x1, 6);  x1 ^= x0;
    x0 += ks1; x1 += ks2 + 1u;
    x0 += x1; x1 = rotl32(x1, 17); x1 ^= x0;
    x0 += x1; x1 = rotl32(x1, 29); x1 ^= x0;
    x0 += x1; x1 = rotl32(x1, 16); x1 ^= x0;
    x0 += x1; x1 = rotl32(x1, 24); x1 ^= x0;
    x0 += ks2; x1 += ks0 + 2u;
    x0 += x1; x1 = rotl32(x1, 13); x1 ^= x0;
    x0 += x1; x1 = rotl32(x1, 15); x1 ^= x0;
    x0 += x1; x1 = rotl32(x1, 26); x1 ^= x0;
    x0 += x1; x1 = rotl32(x1, 6);  x1 ^= x0;
    x0 += ks0; x1 += ks1 + 3u;
    x0 += x1; x1 = rotl32(x1, 17); x1 ^= x0;
    x0 += x1; x1 = rotl32(x1, 29); x1 ^= x0;
    x0 += x1; x1 = rotl32(x1, 16); x1 ^= x0;
    x0 += x1; x1 = rotl32(x1, 24); x1 ^= x0;
    x0 += ks1; x1 += ks2 + 4u;
    x0 += x1; x1 = rotl32(x1, 13); x1 ^= x0;
    x0 += x1; x1 = rotl32(x1, 15); x1 ^= x0;
    x0 += x1; x1 = rotl32(x1, 26); x1 ^= x0;
    x0 += x1; x1 = rotl32(x1, 6);  x1 ^= x0;
    x0 += ks2; x1 += ks0 + 5u;
    return x0 ^ x1;
}

// Unnormalized weight q = exp(x*invT - xm). Monotone in p; identical formula
// in every pass => bit-identical q per element (determinism requirement).
__device__ __forceinline__ float q_of(float x, float invT, float xm) {
    return __expf(fmaf(x, invT, -xm));
}

__device__ __forceinline__ float noise_of(uint32_t j) {
    uint32_t bits = threefry_bits(j);
    float u = __uint_as_float((bits >> 9) | 0x3F800000u) - 1.0f;
    return fmaxf(-log1pf(-u), 1e-10f);
}

extern "C" __global__ void __launch_bounds__(NT, 1)
sampler_kernel(const float* __restrict__ logits,
               const float* __restrict__ temps,
               const float* __restrict__ topps,
               int* __restrict__ out)
{
    const int row = blockIdx.x;
    const int tid = threadIdx.x;
    const int lane = tid & 63;
    const int wid = tid >> 6;
    const float* L = logits + (size_t)row * VV;
    const float4* L4 = (const float4*)L;

    // 32KB phase-aliased LDS: hist fp32[4096] (pass B) / sortbuf ull[4096] (pass C)
    __shared__ __align__(16) unsigned char SMEM[32768];
    float* hist = (float*)SMEM;
    unsigned long long* sortbuf = (unsigned long long*)SMEM;

    __shared__ double wtot[NWAVE];
    __shared__ float wredf[NWAVE];
    __shared__ int wredi[NWAVE];
    __shared__ float sh_lmax;
    __shared__ int sh_gidx;
    __shared__ double sh_cutZ;
    __shared__ double sh_M;
    __shared__ int sh_bstar;
    __shared__ int sh_ng;
    __shared__ int sh_jstar;

    const float Traw = temps[row];
    const float T = fmaxf(Traw, 1e-5f);
    const float invT = 1.0f / T;
    const float tp = topps[row];

    // ---------------- Pass A: max + argmax of raw logits ----------------
    float lmax = -3.402823466e38f; int lidx = 0x7FFFFFFF;
    for (int iv = tid; iv < NV4; iv += NT) {
        float4 x = L4[iv];
        float m4 = fmaxf(fmaxf(x.x, x.y), fmaxf(x.z, x.w));
        if (m4 > lmax) {          // strict > keeps first occurrence
            int base = iv * 4;
            if      (x.x == m4) lidx = base;
            else if (x.y == m4) lidx = base + 1;
            else if (x.z == m4) lidx = base + 2;
            else                lidx = base + 3;
            lmax = m4;
        }
    }
    for (int off = 32; off > 0; off >>= 1) {
        float ov = __shfl_down(lmax, off);
        int   oi = __shfl_down(lidx, off);
        if (ov > lmax || (ov == lmax && oi < lidx)) { lmax = ov; lidx = oi; }
    }
    if (lane == 0) { wredf[wid] = lmax; wredi[wid] = lidx; }
    // zero hist while the reduce lands (completes before the barrier)
    for (int i = tid; i < NBUCK; i += NT) hist[i] = 0.0f;
    __syncthreads();
    if (wid == 0) {
        float v = (lane < NWAVE) ? wredf[lane] : -3.402823466e38f;
        int   i = (lane < NWAVE) ? wredi[lane] : 0x7FFFFFFF;
        for (int off = 32; off > 0; off >>= 1) {
            float ov = __shfl_down(v, off);
            int   oi = __shfl_down(i, off);
            if (ov > v || (ov == v && oi < i)) { v = ov; i = oi; }
        }
        if (lane == 0) { sh_lmax = v; sh_gidx = i; }
    }
    __syncthreads();
    const float xm = sh_lmax * invT;
    const int gidx = sh_gidx;
    // bucket of the top token (q_top may be != 1.0 exactly due to fma rounding)
    const int btop = (int)(__float_as_uint(q_of(sh_lmax, invT, xm)) >> 18);

    // ---------------- Pass B: fp32 bucket-mass histogram of q ----------------
    for (int iv = tid; iv < NV4; iv += NT) {
        float4 x = L4[iv];
        float q0 = q_of(x.x, invT, xm);
        float q1 = q_of(x.y, invT, xm);
        float q2 = q_of(x.z, invT, xm);
        float q3 = q_of(x.w, invT, xm);
        unsigned b0 = __float_as_uint(q0);
        unsigned b1 = __float_as_uint(q1);
        unsigned b2 = __float_as_uint(q2);
        unsigned b3 = __float_as_uint(q3);
        if (b0) atomicAdd(&hist[b0 >> 18], q0);
        if (b1) atomicAdd(&hist[b1 >> 18], q1);
        if (b2) atomicAdd(&hist[b2 >> 18], q2);
        if (b3) atomicAdd(&hist[b3 >> 18], q3);
    }
    __syncthreads();

    // Hierarchical fp64 suffix-scan over 4096 buckets; thread t owns 4t..4t+3.
    float h0 = hist[4 * tid], h1 = hist[4 * tid + 1],
          h2 = hist[4 * tid + 2], h3 = hist[4 * tid + 3];
    double s3 = (double)h3;
    double s2 = s3 + (double)h2;
    double s1 = s2 + (double)h1;
    double s0 = s1 + (double)h0;
    double incl = s0;
    for (int off = 1; off < 64; off <<= 1) {
        double u = __shfl_down(incl, off);
        if (lane + off < 64) incl += u;
    }
    double excl = __shfl_down(incl, 1);
    if (lane == 63) excl = 0.0;
    if (lane == 0) wtot[wid] = incl;
    __syncthreads();
    double cw = 0.0;
    for (int w = wid + 1; w < NWAVE; w++) cw += wtot[w];
    const double carry = excl + cw;     // suffix mass of buckets >= 4(t+1)
    if (tid == 0) {
        double Z = s0 + carry;          // total mass
        sh_cutZ = (double)tp * Z;
        sh_bstar = -1;
        sh_M = 0.0;
        sh_ng = 0;
        sh_jstar = 0x7FFFFFFF;
    }
    __syncthreads();
    const double cutZ = sh_cutZ;
    {
        double S0 = s0 + carry, S1 = s1 + carry, S2 = s2 + carry, S3 = s3 + carry;
        // crossing bucket b*: S_b > cutZ && S_{b+1} <= cutZ (S monotone non-incr)
        if (S0 > cutZ && S1 <= cutZ)    { sh_bstar = 4 * tid;     sh_M = S1; }
        if (S1 > cutZ && S2 <= cutZ)    { sh_bstar = 4 * tid + 1; sh_M = S2; }
        if (S2 > cutZ && S3 <= cutZ)    { sh_bstar = 4 * tid + 2; sh_M = S3; }
        if (S3 > cutZ && carry <= cutZ) { sh_bstar = 4 * tid + 3; sh_M = carry; }
    }
    __syncthreads();
    const int bstar = sh_bstar;
    const double M = sh_M;

    // ---------------- Pass C: above-bucket race + crossing-bucket gather ----
    float bs = -1.0f; int bi = 0x7FFFFFFF;
    const uint32_t jbase = (uint32_t)row * (uint32_t)VV;
    for (int iv = tid; iv < NV4; iv += NT) {
        float4 x = L4[iv];
        float q0 = q_of(x.x, invT, xm);
        float q1 = q_of(x.y, invT, xm);
        float q2 = q_of(x.z, invT, xm);
        float q3 = q_of(x.w, invT, xm);
        int base = iv * 4;
        float qs[4] = {q0, q1, q2, q3};
        #pragma unroll
        for (int k = 0; k < 4; k++) {
            unsigned pb = __float_as_uint(qs[k]);
            if (pb == 0u) continue;                 // zero-prob: can never win
            int b = (int)(pb >> 18);
            if (b > bstar) {                        // unconditionally kept
                int v = base + k;
                float nz = noise_of(jbase + (uint32_t)v);
                float sc = __fdividef(qs[k], nz);
                if (sc > bs || (sc == bs && v < bi)) { bs = sc; bi = v; }
            } else if (b == bstar) {                // crossing bucket: gather
                int pos = atomicAdd(&sh_ng, 1);
                if (pos < CAP)
                    sortbuf[pos] = ((unsigned long long)pb << 32)
                                 | (unsigned)(~(unsigned)(base + k));
            }
        }
    }
    __syncthreads();

    if (bstar >= 0) {
        int n = sh_ng; if (n > CAP) n = CAP;        // overflow ~impossible (<~1.5k)
        int npad = 4; while (npad < n) npad <<= 1;
        for (int i = tid; i < npad; i += NT) if (i >= n) sortbuf[i] = 0ULL;
        __syncthreads();
        // bitonic sort desc by (q, ~idx); keys unique => deterministic order
        for (int k = 2; k <= npad; k <<= 1) {
            for (int j = k >> 1; j > 0; j >>= 1) {
                for (int i = tid; i < npad; i += NT) {
                    int p = i ^ j;
                    if (p > i) {
                        unsigned long long a = sortbuf[i], b2 = sortbuf[p];
                        bool desc = ((i & k) == 0);
                        if (desc ? (a < b2) : (a > b2)) { sortbuf[i] = b2; sortbuf[p] = a; }
                    }
                }
                __syncthreads();
            }
        }
        // forward inclusive fp64 scan of q over sorted slots (4/thread + wave + block)
        double f0 = 0.0, f1 = 0.0, f2 = 0.0, f3 = 0.0;
        int t4 = tid * 4;
        if (t4 < npad) {
            f0 = (double)__uint_as_float((unsigned)(sortbuf[t4]     >> 32));
            f1 = (double)__uint_as_float((unsigned)(sortbuf[t4 + 1] >> 32));
            f2 = (double)__uint_as_float((unsigned)(sortbuf[t4 + 2] >> 32));
            f3 = (double)__uint_as_float((unsigned)(sortbuf[t4 + 3] >> 32));
        }
        double c0 = f0, c1 = c0 + f1, c2 = c1 + f2, c3 = c2 + f3;
        double incl2 = c3;
        for (int off = 1; off < 64; off <<= 1) {
            double u = __shfl_up(incl2, off);
            if (lane >= off) incl2 += u;
        }
        double excl2 = __shfl_up(incl2, 1);
        if (lane == 0) excl2 = 0.0;
        double wt = __shfl(incl2, 63);
        if (lane == 0) wtot[wid] = wt;
        __syncthreads();
        double cw2 = 0.0;
        for (int w = 0; w < wid; w++) cw2 += wtot[w];
        double cr = cw2 + excl2;
        if (t4 < npad) {
            // rank r masked iff M + cumsum_incl(r) > cutZ; jstar = first masked
            bool m0 = (M + (cr + c0)) > cutZ;
            bool m1 = (M + (cr + c1)) > cutZ;
            bool m2 = (M + (cr + c2)) > cutZ;
            bool m3 = (M + (cr + c3)) > cutZ;
            int cand = m0 ? t4 : m1 ? (t4 + 1) : m2 ? (t4 + 2) : m3 ? (t4 + 3)
                                                                    : 0x7FFFFFFF;
            if (cand != 0x7FFFFFFF) atomicMin(&sh_jstar, cand);
        }
        __syncthreads();
        int jstar = sh_jstar; if (jstar > n) jstar = n;
        // ref forces mask[:,0]=False: if nothing kept and nothing above, keep rank 0
        if (jstar == 0 && bstar == btop) jstar = 1;
        // race the kept crossing-bucket members
        for (int i = tid; i < jstar; i += NT) {
            unsigned long long key = sortbuf[i];
            float qq = __uint_as_float((unsigned)(key >> 32));
            int v = (int)(~(unsigned)key);
            float nz = noise_of(jbase + (uint32_t)v);
            float sc = __fdividef(qq, nz);
            if (sc > bs || (sc == bs && v < bi)) { bs = sc; bi = v; }
        }
    }

    // ---------------- final block argmax (score desc, index asc) ------------
    for (int off = 32; off > 0; off >>= 1) {
        float ov = __shfl_down(bs, off);
        int   oi = __shfl_down(bi, off);
        if (ov > bs || (ov == bs && oi < bi)) { bs = ov; bi = oi; }
    }
    if (lane == 0) { wredf[wid] = bs; wredi[wid] = bi; }
    __syncthreads();
    if (tid == 0) {
        float v = wredf[0]; int i = wredi[0];
        for (int w = 1; w < NWAVE; w++) {
            float ov = wredf[w]; int oi = wredi[w];
            if (ov > v || (ov == v && oi < i)) { v = ov; i = oi; }
        }
        out[row] = (Traw <= 1e-10f) ? gidx : i;
    }
}

extern "C" void kernel_launch(void* const* d_in, const int* in_sizes, int n_in,
                              void* d_out, int out_size, void* d_ws, size_t ws_size,
                              hipStream_t stream) {
    const float* logits = (const float*)d_in[0];
    const float* temps = (const float*)d_in[1];
    const float* topps = (const float*)d_in[2];
    int* out = (int*)d_out;
    (void)in_sizes; (void)n_in; (void)out_size; (void)d_ws; (void)ws_size;
    sampler_kernel<<<dim3(BB), dim3(NT), 0, stream>>>(logits, temps, topps, out);
}

// Round 3
// 528.699 us; speedup vs baseline: 1.3509x; 1.0905x over previous
//
#include <hip/hip_runtime.h>
#include <stdint.h>

typedef unsigned long long u64;
typedef uint32_t u32;

#define BB 256
#define VV 128000
#define NV4 (VV / 4)          // 32000 float4 per row
#define SLICES 16
#define SL4 (NV4 / SLICES)    // 2000 float4 per slice
#define NBUCK 4096
#define CAP 2048              // crossing-bucket worst case ~600 (T<1); 3x headroom

// ---- workspace layout (bytes) ----
#define OFF_SMAX 0                         // float[256*16]
#define OFF_SARG (16*1024)                 // int[256*16]
#define OFF_WWIN (32*1024)                 // u64[256*16]  (K4 writes all slots)
#define OFF_PAR  (64*1024)                 // RowPar[256]
#define OFF_CNT  (72*1024)                 // int[256]     (memset 0)
#define OFF_HIST (80*1024)                 // float[256*4096] (memset 0)
#define OFF_LIST (OFF_HIST + BB*NBUCK*4)   // u64[256*CAP]
#define WS_TOTAL (OFF_LIST + (size_t)BB*CAP*8)

struct RowPar { int bstar; int pad; double M; double cutZ; };

__device__ __forceinline__ u32 rotl32(u32 v, u32 r) { return (v << r) | (v >> (32u - r)); }

// JAX partitionable threefry, key=(0,1), ctr=(0,j), bits=o0^o1.
// Verified bit-exact (R1/R2 absmax 0). DO NOT TOUCH.
__device__ __forceinline__ u32 threefry_bits(u32 j) {
    const u32 ks0 = 0u, ks1 = 1u, ks2 = 0x1BD11BDBu;
    u32 x0 = ks0, x1 = j + ks1;
    x0 += x1; x1 = rotl32(x1, 13); x1 ^= x0;
    x0 += x1; x1 = rotl32(x1, 15); x1 ^= x0;
    x0 += x1; x1 = rotl32(x1, 26); x1 ^= x0;
    x0 += x1; x1 = rotl32(x1, 6);  x1 ^= x0;
    x0 += ks1; x1 += ks2 + 1u;
    x0 += x1; x1 = rotl32(x1, 17); x1 ^= x0;
    x0 += x1; x1 = rotl32(x1, 29); x1 ^= x0;
    x0 += x1; x1 = rotl32(x1, 16); x1 ^= x0;
    x0 += x1; x1 = rotl32(x1, 24); x1 ^= x0;
    x0 += ks2; x1 += ks0 + 2u;
    x0 += x1; x1 = rotl32(x1, 13); x1 ^= x0;
    x0 += x1; x1 = rotl32(x1, 15); x1 ^= x0;
    x0 += x1; x1 = rotl32(x1, 26); x1 ^= x0;
    x0 += x1; x1 = rotl32(x1, 6);  x1 ^= x0;
    x0 += ks0; x1 += ks1 + 3u;
    x0 += x1; x1 = rotl32(x1, 17); x1 ^= x0;
    x0 += x1; x1 = rotl32(x1, 29); x1 ^= x0;
    x0 += x1; x1 = rotl32(x1, 16); x1 ^= x0;
    x0 += x1; x1 = rotl32(x1, 24); x1 ^= x0;
    x0 += ks1; x1 += ks2 + 4u;
    x0 += x1; x1 = rotl32(x1, 13); x1 ^= x0;
    x0 += x1; x1 = rotl32(x1, 15); x1 ^= x0;
    x0 += x1; x1 = rotl32(x1, 26); x1 ^= x0;
    x0 += x1; x1 = rotl32(x1, 6);  x1 ^= x0;
    x0 += ks2; x1 += ks0 + 5u;
    return x0 ^ x1;
}

__device__ __forceinline__ float q_of(float x, float invT, float xm) {
    return __expf(fmaf(x, invT, -xm));
}

__device__ __forceinline__ float noise_of(u32 j) {
    u32 bits = threefry_bits(j);
    float u = __uint_as_float((bits >> 9) | 0x3F800000u) - 1.0f;
    return fmaxf(-log1pf(-u), 1e-10f);
}

// ---------------- K1: per-slice max + argmax ----------------
extern "C" __global__ void __launch_bounds__(256)
k1_stats(const float* __restrict__ logits, float* __restrict__ smax, int* __restrict__ sarg) {
    int blk = blockIdx.x, r = blk >> 4, s = blk & 15;
    int tid = threadIdx.x, lane = tid & 63, wid = tid >> 6;
    __shared__ float sf[4]; __shared__ int si[4];
    const float4* L4 = (const float4*)(logits + (size_t)r * VV);
    int lo = s * SL4, hi = lo + SL4;
    float m = -3.402823466e38f; int mi = 0x7FFFFFFF;
    for (int iv = lo + tid; iv < hi; iv += 256) {
        float4 x = L4[iv];
        float m4 = fmaxf(fmaxf(x.x, x.y), fmaxf(x.z, x.w));
        if (m4 > m) {   // strict > keeps first occurrence
            int base = iv * 4;
            if      (x.x == m4) mi = base;
            else if (x.y == m4) mi = base + 1;
            else if (x.z == m4) mi = base + 2;
            else                mi = base + 3;
            m = m4;
        }
    }
    for (int off = 32; off; off >>= 1) {
        float ov = __shfl_down(m, off); int oi = __shfl_down(mi, off);
        if (ov > m || (ov == m && oi < mi)) { m = ov; mi = oi; }
    }
    if (lane == 0) { sf[wid] = m; si[wid] = mi; }
    __syncthreads();
    if (tid == 0) {
        for (int w = 1; w < 4; w++) {
            float ov = sf[w]; int oi = si[w];
            if (ov > m || (ov == m && oi < mi)) { m = ov; mi = oi; }
        }
        smax[blk] = m; sarg[blk] = mi;
    }
}

// ---------------- K2: per-slice LDS hist -> global fp32 atomic merge ----------------
extern "C" __global__ void __launch_bounds__(256)
k2_hist(const float* __restrict__ logits, const float* __restrict__ smax,
        const float* __restrict__ temps, float* __restrict__ Whist) {
    __shared__ float lh[NBUCK];
    int blk = blockIdx.x, r = blk >> 4, s = blk & 15, tid = threadIdx.x;
    for (int i = tid; i < NBUCK; i += 256) lh[i] = 0.0f;
    float T = fmaxf(temps[r], 1e-5f), invT = 1.0f / T;
    float rm = -3.402823466e38f;
    for (int j = 0; j < 16; j++) rm = fmaxf(rm, smax[r * 16 + j]);
    float xm = rm * invT;
    __syncthreads();
    const float4* L4 = (const float4*)(logits + (size_t)r * VV);
    int lo = s * SL4, hi = lo + SL4;
    for (int iv = lo + tid; iv < hi; iv += 256) {
        float4 x = L4[iv];
        float xs[4] = {x.x, x.y, x.z, x.w};
        #pragma unroll
        for (int k = 0; k < 4; k++) {
            float t = fmaf(xs[k], invT, -xm);
            if (t < -104.0f) continue;        // q bits would be exactly 0
            float q = __expf(t);
            u32 pb = __float_as_uint(q);
            if (pb) atomicAdd(&lh[pb >> 18], q);
        }
    }
    __syncthreads();
    float* gh = Whist + (size_t)r * NBUCK;
    for (int i = tid; i < NBUCK; i += 256) {
        float v = lh[i];
        if (v != 0.0f) atomicAdd(&gh[i], v);
    }
}

// ---------------- K3: per-row suffix scan + cut ----------------
extern "C" __global__ void __launch_bounds__(1024)
k3_cut(const float* __restrict__ Whist, const float* __restrict__ topps,
       RowPar* __restrict__ par) {
    int r = blockIdx.x, tid = threadIdx.x, lane = tid & 63, wid = tid >> 6;
    __shared__ double wtot[16];
    __shared__ double sh_cutZ; __shared__ int sh_b; __shared__ double sh_M;
    float4 h = ((const float4*)(Whist + (size_t)r * NBUCK))[tid];
    double s3 = (double)h.w, s2 = s3 + (double)h.z,
           s1 = s2 + (double)h.y, s0 = s1 + (double)h.x;
    double incl = s0;
    for (int off = 1; off < 64; off <<= 1) {
        double u = __shfl_down(incl, off);
        if (lane + off < 64) incl += u;
    }
    double excl = __shfl_down(incl, 1); if (lane == 63) excl = 0.0;
    if (lane == 0) wtot[wid] = incl;
    if (tid == 0) { sh_b = -1; sh_M = 0.0; }
    __syncthreads();
    double cw = 0.0;
    for (int w = wid + 1; w < 16; w++) cw += wtot[w];
    double carry = excl + cw;
    if (tid == 0) sh_cutZ = (double)topps[r] * (s0 + carry);  // tid0: s0+carry == Z
    __syncthreads();
    double cutZ = sh_cutZ;
    double S0 = s0 + carry, S1 = s1 + carry, S2 = s2 + carry, S3 = s3 + carry;
    if (S0 > cutZ && S1 <= cutZ)    { sh_b = 4 * tid;     sh_M = S1; }
    if (S1 > cutZ && S2 <= cutZ)    { sh_b = 4 * tid + 1; sh_M = S2; }
    if (S2 > cutZ && S3 <= cutZ)    { sh_b = 4 * tid + 2; sh_M = S3; }
    if (S3 > cutZ && carry <= cutZ) { sh_b = 4 * tid + 3; sh_M = carry; }
    __syncthreads();
    if (tid == 0) { RowPar p; p.bstar = sh_b; p.pad = 0; p.M = sh_M; p.cutZ = cutZ; par[r] = p; }
}

// ---------------- K4: per-slice race (above-bucket) + crossing gather ----------------
extern "C" __global__ void __launch_bounds__(256)
k4_race(const float* __restrict__ logits, const float* __restrict__ smax,
        const float* __restrict__ temps, const RowPar* __restrict__ par,
        int* __restrict__ Wcnt, u64* __restrict__ Wlist, u64* __restrict__ Wwin) {
    int blk = blockIdx.x, r = blk >> 4, s = blk & 15;
    int tid = threadIdx.x, lane = tid & 63, wid = tid >> 6;
    __shared__ u64 wred[4];
    float T = fmaxf(temps[r], 1e-5f), invT = 1.0f / T;
    float rm = -3.402823466e38f;
    for (int j = 0; j < 16; j++) rm = fmaxf(rm, smax[r * 16 + j]);
    float xm = rm * invT;
    int bstar = par[r].bstar;
    const float4* L4 = (const float4*)(logits + (size_t)r * VV);
    u32 jbase = (u32)r * (u32)VV;
    u64 pk = 0ULL;
    int lo = s * SL4, hi = lo + SL4;
    for (int iv = lo + tid; iv < hi; iv += 256) {
        float4 x = L4[iv];
        float xs[4] = {x.x, x.y, x.z, x.w};
        int base = iv * 4;
        #pragma unroll
        for (int k = 0; k < 4; k++) {
            float t = fmaf(xs[k], invT, -xm);
            if (t < -104.0f) continue;        // q bits exactly 0 -> never kept
            float q = __expf(t);
            u32 pb = __float_as_uint(q);
            if (!pb) continue;
            int b = (int)(pb >> 18);
            if (b > bstar) {
                u32 v = (u32)(base + k);
                float nz = noise_of(jbase + v);
                float sc = __fdividef(q, nz);
                u64 e = ((u64)__float_as_uint(sc) << 32) | (u64)(~v);
                if (e > pk) pk = e;
            } else if (b == bstar) {
                int pos = atomicAdd(&Wcnt[r], 1);
                if (pos < CAP)
                    Wlist[(size_t)r * CAP + pos] = ((u64)pb << 32) | (u64)(~(u32)(base + k));
            }
        }
    }
    for (int off = 32; off; off >>= 1) { u64 o = __shfl_down(pk, off); if (o > pk) pk = o; }
    if (lane == 0) wred[wid] = pk;
    __syncthreads();
    if (tid == 0) {
        for (int w = 1; w < 4; w++) if (wred[w] > pk) pk = wred[w];
        Wwin[blk] = pk;   // 0 sentinel loses to any real entry
    }
}

// ---------------- K5: per-row sort + exact cut + final race/merge ----------------
extern "C" __global__ void __launch_bounds__(1024)
k5_final(const float* __restrict__ smax, const int* __restrict__ sarg,
         const float* __restrict__ temps, const float* __restrict__ topps,
         const RowPar* __restrict__ par, const int* __restrict__ Wcnt,
         const u64* __restrict__ Wlist, const u64* __restrict__ Wwin,
         int* __restrict__ out) {
    int r = blockIdx.x, tid = threadIdx.x, lane = tid & 63, wid = tid >> 6;
    __shared__ u64 sb[CAP];
    __shared__ double wtot[16];
    __shared__ u64 wred[16];
    __shared__ int sh_js, sh_n, sh_gidx; __shared__ float sh_rm;
    RowPar p = par[r];
    if (tid == 0) {
        float rm = -3.402823466e38f; int gi = 0x7FFFFFFF;
        for (int j = 0; j < 16; j++) {
            float v = smax[r * 16 + j];
            if (v > rm) { rm = v; gi = sarg[r * 16 + j]; }   // earlier slice wins ties
        }
        sh_rm = rm; sh_gidx = gi;
        int n = Wcnt[r]; if (n > CAP) n = CAP; sh_n = n;
        sh_js = 0x7FFFFFFF;
    }
    __syncthreads();
    int n = sh_n;
    int npad = 4; while (npad < n) npad <<= 1;
    const u64* lst = Wlist + (size_t)r * CAP;
    for (int i = tid; i < npad; i += 1024) sb[i] = (i < n) ? lst[i] : 0ULL;
    __syncthreads();
    for (int k = 2; k <= npad; k <<= 1) {
        for (int j = k >> 1; j > 0; j >>= 1) {
            for (int i = tid; i < npad; i += 1024) {
                int q2 = i ^ j;
                if (q2 > i) {
                    u64 a = sb[i], b = sb[q2];
                    bool desc = ((i & k) == 0);
                    if (desc ? (a < b) : (a > b)) { sb[i] = b; sb[q2] = a; }
                }
            }
            __syncthreads();
        }
    }
    // fp64 forward scan (2 elems/thread), find first masked rank
    int t2 = tid * 2;
    double f0 = 0.0, f1 = 0.0;
    if (t2 < npad) {
        f0 = (double)__uint_as_float((u32)(sb[t2] >> 32));
        f1 = (double)__uint_as_float((u32)(sb[t2 + 1] >> 32));
    }
    double c0 = f0, c1 = c0 + f1;
    double incl = c1;
    for (int off = 1; off < 64; off <<= 1) {
        double u = __shfl_up(incl, off);
        if (lane >= off) incl += u;
    }
    double excl = __shfl_up(incl, 1); if (lane == 0) excl = 0.0;
    double wt = __shfl(incl, 63);
    if (lane == 0) wtot[wid] = wt;
    __syncthreads();
    double cw = 0.0;
    for (int w = 0; w < wid; w++) cw += wtot[w];
    double cr = cw + excl;
    if (t2 < npad) {
        bool m0 = (p.M + (cr + c0)) > p.cutZ;
        bool m1 = (p.M + (cr + c1)) > p.cutZ;
        int cand = m0 ? t2 : m1 ? (t2 + 1) : 0x7FFFFFFF;
        if (cand != 0x7FFFFFFF) atomicMin(&sh_js, cand);
    }
    __syncthreads();
    float Traw = temps[r];
    if (tid == 0) {
        int js = sh_js; if (js > n) js = n;
        float T = fmaxf(Traw, 1e-5f), invT = 1.0f / T, xm = sh_rm * invT;
        int btop = (int)(__float_as_uint(q_of(sh_rm, invT, xm)) >> 18);
        if (js == 0 && p.bstar == btop) js = 1;   // mask[:,0]=False
        sh_js = js;
    }
    __syncthreads();
    int js = sh_js;
    u32 jbase = (u32)r * (u32)VV;
    u64 pk = 0ULL;
    for (int i = tid; i < js; i += 1024) {
        u64 key = sb[i];
        float qq = __uint_as_float((u32)(key >> 32));
        u32 v = ~(u32)key;
        float nz = noise_of(jbase + v);
        float sc = __fdividef(qq, nz);
        u64 e = ((u64)__float_as_uint(sc) << 32) | (u64)(~v);
        if (e > pk) pk = e;
    }
    if (tid < 16) { u64 w = Wwin[r * 16 + tid]; if (w > pk) pk = w; }
    for (int off = 32; off; off >>= 1) { u64 o = __shfl_down(pk, off); if (o > pk) pk = o; }
    if (lane == 0) wred[wid] = pk;
    __syncthreads();
    if (tid == 0) {
        for (int w = 1; w < 16; w++) if (wred[w] > pk) pk = wred[w];
        int bi = (int)(~(u32)pk);
        out[r] = (Traw <= 1e-10f) ? sh_gidx : bi;
    }
}

// ---------------- fallback: verified R2 monolithic kernel ----------------
extern "C" __global__ void __launch_bounds__(1024, 1)
sampler_fallback(const float* __restrict__ logits, const float* __restrict__ temps,
                 const float* __restrict__ topps, int* __restrict__ out)
{
    const int row = blockIdx.x;
    const int tid = threadIdx.x;
    const int lane = tid & 63;
    const int wid = tid >> 6;
    const float* L = logits + (size_t)row * VV;
    const float4* L4 = (const float4*)L;
    __shared__ __align__(16) unsigned char SMEM[32768];
    float* hist = (float*)SMEM;
    u64* sortbuf = (u64*)SMEM;
    __shared__ double wtot[16];
    __shared__ float wredf[16];
    __shared__ int wredi[16];
    __shared__ float sh_lmax;
    __shared__ int sh_gidx;
    __shared__ double sh_cutZ;
    __shared__ double sh_M;
    __shared__ int sh_bstar;
    __shared__ int sh_ng;
    __shared__ int sh_jstar;
    const float Traw = temps[row];
    const float T = fmaxf(Traw, 1e-5f);
    const float invT = 1.0f / T;
    const float tp = topps[row];
    float lmax = -3.402823466e38f; int lidx = 0x7FFFFFFF;
    for (int iv = tid; iv < NV4; iv += 1024) {
        float4 x = L4[iv];
        float m4 = fmaxf(fmaxf(x.x, x.y), fmaxf(x.z, x.w));
        if (m4 > lmax) {
            int base = iv * 4;
            if      (x.x == m4) lidx = base;
            else if (x.y == m4) lidx = base + 1;
            else if (x.z == m4) lidx = base + 2;
            else                lidx = base + 3;
            lmax = m4;
        }
    }
    for (int off = 32; off > 0; off >>= 1) {
        float ov = __shfl_down(lmax, off);
        int   oi = __shfl_down(lidx, off);
        if (ov > lmax || (ov == lmax && oi < lidx)) { lmax = ov; lidx = oi; }
    }
    if (lane == 0) { wredf[wid] = lmax; wredi[wid] = lidx; }
    for (int i = tid; i < NBUCK; i += 1024) hist[i] = 0.0f;
    __syncthreads();
    if (wid == 0) {
        float v = (lane < 16) ? wredf[lane] : -3.402823466e38f;
        int   i = (lane < 16) ? wredi[lane] : 0x7FFFFFFF;
        for (int off = 32; off > 0; off >>= 1) {
            float ov = __shfl_down(v, off);
            int   oi = __shfl_down(i, off);
            if (ov > v || (ov == v && oi < i)) { v = ov; i = oi; }
        }
        if (lane == 0) { sh_lmax = v; sh_gidx = i; }
    }
    __syncthreads();
    const float xm = sh_lmax * invT;
    const int gidx = sh_gidx;
    const int btop = (int)(__float_as_uint(q_of(sh_lmax, invT, xm)) >> 18);
    for (int iv = tid; iv < NV4; iv += 1024) {
        float4 x = L4[iv];
        float q0 = q_of(x.x, invT, xm), q1 = q_of(x.y, invT, xm);
        float q2 = q_of(x.z, invT, xm), q3 = q_of(x.w, invT, xm);
        u32 b0 = __float_as_uint(q0), b1 = __float_as_uint(q1);
        u32 b2 = __float_as_uint(q2), b3 = __float_as_uint(q3);
        if (b0) atomicAdd(&hist[b0 >> 18], q0);
        if (b1) atomicAdd(&hist[b1 >> 18], q1);
        if (b2) atomicAdd(&hist[b2 >> 18], q2);
        if (b3) atomicAdd(&hist[b3 >> 18], q3);
    }
    __syncthreads();
    float h0 = hist[4 * tid], h1 = hist[4 * tid + 1],
          h2 = hist[4 * tid + 2], h3 = hist[4 * tid + 3];
    double s3 = (double)h3, s2 = s3 + (double)h2, s1 = s2 + (double)h1, s0 = s1 + (double)h0;
    double incl = s0;
    for (int off = 1; off < 64; off <<= 1) {
        double u = __shfl_down(incl, off);
        if (lane + off < 64) incl += u;
    }
    double excl = __shfl_down(incl, 1);
    if (lane == 63) excl = 0.0;
    if (lane == 0) wtot[wid] = incl;
    __syncthreads();
    double cw = 0.0;
    for (int w = wid + 1; w < 16; w++) cw += wtot[w];
    const double carry = excl + cw;
    if (tid == 0) {
        sh_cutZ = (double)tp * (s0 + carry);
        sh_bstar = -1; sh_M = 0.0; sh_ng = 0; sh_jstar = 0x7FFFFFFF;
    }
    __syncthreads();
    const double cutZ = sh_cutZ;
    {
        double S0 = s0 + carry, S1 = s1 + carry, S2 = s2 + carry, S3 = s3 + carry;
        if (S0 > cutZ && S1 <= cutZ)    { sh_bstar = 4 * tid;     sh_M = S1; }
        if (S1 > cutZ && S2 <= cutZ)    { sh_bstar = 4 * tid + 1; sh_M = S2; }
        if (S2 > cutZ && S3 <= cutZ)    { sh_bstar = 4 * tid + 2; sh_M = S3; }
        if (S3 > cutZ && carry <= cutZ) { sh_bstar = 4 * tid + 3; sh_M = carry; }
    }
    __syncthreads();
    const int bstar = sh_bstar;
    const double M = sh_M;
    float bs = -1.0f; int bi = 0x7FFFFFFF;
    const u32 jbase = (u32)row * (u32)VV;
    for (int iv = tid; iv < NV4; iv += 1024) {
        float4 x = L4[iv];
        float qs[4] = {q_of(x.x, invT, xm), q_of(x.y, invT, xm),
                       q_of(x.z, invT, xm), q_of(x.w, invT, xm)};
        int base = iv * 4;
        #pragma unroll
        for (int k = 0; k < 4; k++) {
            u32 pb = __float_as_uint(qs[k]);
            if (pb == 0u) continue;
            int b = (int)(pb >> 18);
            if (b > bstar) {
                int v = base + k;
                float nz = noise_of(jbase + (u32)v);
                float sc = __fdividef(qs[k], nz);
                if (sc > bs || (sc == bs && v < bi)) { bs = sc; bi = v; }
            } else if (b == bstar) {
                int pos = atomicAdd(&sh_ng, 1);
                if (pos < 4096)
                    sortbuf[pos] = ((u64)pb << 32) | (u32)(~(u32)(base + k));
            }
        }
    }
    __syncthreads();
    if (bstar >= 0) {
        int n = sh_ng; if (n > 4096) n = 4096;
        int npad = 4; while (npad < n) npad <<= 1;
        for (int i = tid; i < npad; i += 1024) if (i >= n) sortbuf[i] = 0ULL;
        __syncthreads();
        for (int k = 2; k <= npad; k <<= 1) {
            for (int j = k >> 1; j > 0; j >>= 1) {
                for (int i = tid; i < npad; i += 1024) {
                    int pidx = i ^ j;
                    if (pidx > i) {
                        u64 a = sortbuf[i], b2 = sortbuf[pidx];
                        bool desc = ((i & k) == 0);
                        if (desc ? (a < b2) : (a > b2)) { sortbuf[i] = b2; sortbuf[pidx] = a; }
                    }
                }
                __syncthreads();
            }
        }
        double f0 = 0.0, f1 = 0.0, f2 = 0.0, f3 = 0.0;
        int t4 = tid * 4;
        if (t4 < npad) {
            f0 = (double)__uint_as_float((u32)(sortbuf[t4]     >> 32));
            f1 = (double)__uint_as_float((u32)(sortbuf[t4 + 1] >> 32));
            f2 = (double)__uint_as_float((u32)(sortbuf[t4 + 2] >> 32));
            f3 = (double)__uint_as_float((u32)(sortbuf[t4 + 3] >> 32));
        }
        double c0 = f0, c1 = c0 + f1, c2 = c1 + f2, c3 = c2 + f3;
        double incl2 = c3;
        for (int off = 1; off < 64; off <<= 1) {
            double u = __shfl_up(incl2, off);
            if (lane >= off) incl2 += u;
        }
        double excl2 = __shfl_up(incl2, 1);
        if (lane == 0) excl2 = 0.0;
        double wt = __shfl(incl2, 63);
        if (lane == 0) wtot[wid] = wt;
        __syncthreads();
        double cw2 = 0.0;
        for (int w = 0; w < wid; w++) cw2 += wtot[w];
        double cr = cw2 + excl2;
        if (t4 < npad) {
            bool m0 = (M + (cr + c0)) > cutZ;
            bool m1 = (M + (cr + c1)) > cutZ;
            bool m2 = (M + (cr + c2)) > cutZ;
            bool m3 = (M + (cr + c3)) > cutZ;
            int cand = m0 ? t4 : m1 ? (t4 + 1) : m2 ? (t4 + 2) : m3 ? (t4 + 3) : 0x7FFFFFFF;
            if (cand != 0x7FFFFFFF) atomicMin(&sh_jstar, cand);
        }
        __syncthreads();
        int jstar = sh_jstar; if (jstar > n) jstar = n;
        if (jstar == 0 && bstar == btop) jstar = 1;
        for (int i = tid; i < jstar; i += 1024) {
            u64 key = sortbuf[i];
            float qq = __uint_as_float((u32)(key >> 32));
            int v = (int)(~(u32)key);
            float nz = noise_of(jbase + (u32)v);
            float sc = __fdividef(qq, nz);
            if (sc > bs || (sc == bs && v < bi)) { bs = sc; bi = v; }
        }
    }
    for (int off = 32; off > 0; off >>= 1) {
        float ov = __shfl_down(bs, off);
        int   oi = __shfl_down(bi, off);
        if (ov > bs || (ov == bs && oi < bi)) { bs = ov; bi = oi; }
    }
    if (lane == 0) { wredf[wid] = bs; wredi[wid] = bi; }
    __syncthreads();
    if (tid == 0) {
        float v = wredf[0]; int i = wredi[0];
        for (int w = 1; w < 16; w++) {
            float ov = wredf[w]; int oi = wredi[w];
            if (ov > v || (ov == v && oi < i)) { v = ov; i = oi; }
        }
        out[row] = (Traw <= 1e-10f) ? gidx : i;
    }
}

extern "C" void kernel_launch(void* const* d_in, const int* in_sizes, int n_in,
                              void* d_out, int out_size, void* d_ws, size_t ws_size,
                              hipStream_t stream) {
    const float* logits = (const float*)d_in[0];
    const float* temps = (const float*)d_in[1];
    const float* topps = (const float*)d_in[2];
    int* out = (int*)d_out;
    (void)in_sizes; (void)n_in; (void)out_size;

    if (ws_size >= WS_TOTAL) {
        char* ws = (char*)d_ws;
        float* smax  = (float*)(ws + OFF_SMAX);
        int*   sarg  = (int*)(ws + OFF_SARG);
        u64*   wwin  = (u64*)(ws + OFF_WWIN);
        RowPar* par  = (RowPar*)(ws + OFF_PAR);
        int*   wcnt  = (int*)(ws + OFF_CNT);
        float* whist = (float*)(ws + OFF_HIST);
        u64*   wlist = (u64*)(ws + OFF_LIST);
        hipMemsetAsync(wcnt, 0, BB * sizeof(int), stream);
        hipMemsetAsync(whist, 0, (size_t)BB * NBUCK * sizeof(float), stream);
        k1_stats<<<BB * SLICES, 256, 0, stream>>>(logits, smax, sarg);
        k2_hist<<<BB * SLICES, 256, 0, stream>>>(logits, smax, temps, whist);
        k3_cut<<<BB, 1024, 0, stream>>>(whist, topps, par);
        k4_race<<<BB * SLICES, 256, 0, stream>>>(logits, smax, temps, par, wcnt, wlist, wwin);
        k5_final<<<BB, 1024, 0, stream>>>(smax, sarg, temps, topps, par, wcnt, wlist, wwin, out);
    } else {
        sampler_fallback<<<BB, 1024, 0, stream>>>(logits, temps, topps, out);
    }
}

// Round 5
// 528.071 us; speedup vs baseline: 1.3525x; 1.0012x over previous
//
#include <hip/hip_runtime.h>
#include <stdint.h>

typedef unsigned long long u64;
typedef uint32_t u32;

#define BB 256
#define VV 128000
#define NV4 (VV / 4)          // 32000 float4 per row
#define SLICES 16
#define SL4 (NV4 / SLICES)    // 2000 float4 per slice (k1/k4)
#define K2S 4                 // k2 slices per row
#define K2SL4 (NV4 / K2S)     // 8000 float4 per k2 slice
#define NBUCK 4096
// Each LDS histogram copy holds HSTRIDE buckets. Real buckets are <= ~4065
// (q <= exp(0.037) bound from |xm|*2^-24 fma rounding), so [4088,4096) is
// structurally empty; global hist keeps those at memset-0.
// 4088 % 32 = 24 -> copy c of bucket b lands in bank (b + 24c) % 32 (all distinct).
#define HSTRIDE 4088
#define NCOPY 4
#define CAP 2048

// ---- workspace layout (bytes) ----
#define OFF_SMAX 0                         // float[256*16]
#define OFF_SARG (16*1024)                 // int[256*16]
#define OFF_WWIN (32*1024)                 // u64[256*16]
#define OFF_PAR  (64*1024)                 // RowPar[256]
#define OFF_CNT  (72*1024)                 // int[256]     (memset 0)
#define OFF_HIST (80*1024)                 // float[256*4096] (memset 0)
#define OFF_LIST (OFF_HIST + BB*NBUCK*4)   // u64[256*CAP]
#define WS_TOTAL (OFF_LIST + (size_t)BB*CAP*8)

struct RowPar { int bstar; int pad; double M; double cutZ; };

__device__ __forceinline__ u32 rotl32(u32 v, u32 r) { return (v << r) | (v >> (32u - r)); }

// JAX partitionable threefry, key=(0,1), ctr=(0,j), bits=o0^o1.
// Verified bit-exact (R1-R3 absmax 0). DO NOT TOUCH.
__device__ __forceinline__ u32 threefry_bits(u32 j) {
    const u32 ks0 = 0u, ks1 = 1u, ks2 = 0x1BD11BDBu;
    u32 x0 = ks0, x1 = j + ks1;
    x0 += x1; x1 = rotl32(x1, 13); x1 ^= x0;
    x0 += x1; x1 = rotl32(x1, 15); x1 ^= x0;
    x0 += x1; x1 = rotl32(x1, 26); x1 ^= x0;
    x0 += x1; x1 = rotl32(x1, 6);  x1 ^= x0;
    x0 += ks1; x1 += ks2 + 1u;
    x0 += x1; x1 = rotl32(x1, 17); x1 ^= x0;
    x0 += x1; x1 = rotl32(x1, 29); x1 ^= x0;
    x0 += x1; x1 = rotl32(x1, 16); x1 ^= x0;
    x0 += x1; x1 = rotl32(x1, 24); x1 ^= x0;
    x0 += ks2; x1 += ks0 + 2u;
    x0 += x1; x1 = rotl32(x1, 13); x1 ^= x0;
    x0 += x1; x1 = rotl32(x1, 15); x1 ^= x0;
    x0 += x1; x1 = rotl32(x1, 26); x1 ^= x0;
    x0 += x1; x1 = rotl32(x1, 6);  x1 ^= x0;
    x0 += ks0; x1 += ks1 + 3u;
    x0 += x1; x1 = rotl32(x1, 17); x1 ^= x0;
    x0 += x1; x1 = rotl32(x1, 29); x1 ^= x0;
    x0 += x1; x1 = rotl32(x1, 16); x1 ^= x0;
    x0 += x1; x1 = rotl32(x1, 24); x1 ^= x0;
    x0 += ks1; x1 += ks2 + 4u;
    x0 += x1; x1 = rotl32(x1, 13); x1 ^= x0;
    x0 += x1; x1 = rotl32(x1, 15); x1 ^= x0;
    x0 += x1; x1 = rotl32(x1, 26); x1 ^= x0;
    x0 += x1; x1 = rotl32(x1, 6);  x1 ^= x0;
    x0 += ks2; x1 += ks0 + 5u;
    return x0 ^ x1;
}

__device__ __forceinline__ float q_of(float x, float invT, float xm) {
    return __expf(fmaf(x, invT, -xm));
}

__device__ __forceinline__ float noise_of(u32 j) {
    u32 bits = threefry_bits(j);
    float u = __uint_as_float((bits >> 9) | 0x3F800000u) - 1.0f;
    return fmaxf(-log1pf(-u), 1e-10f);
}

// ---------------- K1: per-slice max + argmax (2 loads in flight) ----------------
extern "C" __global__ void __launch_bounds__(256)
k1_stats(const float* __restrict__ logits, float* __restrict__ smax, int* __restrict__ sarg) {
    int blk = blockIdx.x, r = blk >> 4, s = blk & 15;
    int tid = threadIdx.x, lane = tid & 63, wid = tid >> 6;
    __shared__ float sf[4]; __shared__ int si[4];
    const float4* L4 = (const float4*)(logits + (size_t)r * VV);
    int lo = s * SL4, hi = lo + SL4;
    float m = -3.402823466e38f; int mi = 0x7FFFFFFF;
    for (int iv = lo + tid; iv < hi; iv += 512) {
        float4 a = L4[iv];
        int iv2 = iv + 256; bool h2 = iv2 < hi;
        float4 b;
        if (h2) b = L4[iv2];
        {
            float m4 = fmaxf(fmaxf(a.x, a.y), fmaxf(a.z, a.w));
            if (m4 > m) {
                int base = iv * 4;
                if      (a.x == m4) mi = base;
                else if (a.y == m4) mi = base + 1;
                else if (a.z == m4) mi = base + 2;
                else                mi = base + 3;
                m = m4;
            }
        }
        if (h2) {
            float m4 = fmaxf(fmaxf(b.x, b.y), fmaxf(b.z, b.w));
            if (m4 > m) {
                int base = iv2 * 4;
                if      (b.x == m4) mi = base;
                else if (b.y == m4) mi = base + 1;
                else if (b.z == m4) mi = base + 2;
                else                mi = base + 3;
                m = m4;
            }
        }
    }
    for (int off = 32; off; off >>= 1) {
        float ov = __shfl_down(m, off); int oi = __shfl_down(mi, off);
        if (ov > m || (ov == m && oi < mi)) { m = ov; mi = oi; }
    }
    if (lane == 0) { sf[wid] = m; si[wid] = mi; }
    __syncthreads();
    if (tid == 0) {
        for (int w = 1; w < 4; w++) {
            float ov = sf[w]; int oi = si[w];
            if (ov > m || (ov == m && oi < mi)) { m = ov; mi = oi; }
        }
        smax[blk] = m; sarg[blk] = mi;
    }
}

// ---------------- K2: 4x-replicated LDS hist, 4 loads in flight ----------------
extern "C" __global__ void __launch_bounds__(1024)
k2_hist(const float* __restrict__ logits, const float* __restrict__ smax,
        const float* __restrict__ temps, float* __restrict__ Whist) {
    __shared__ float lh[NCOPY * HSTRIDE];           // 65,408 B
    int blk = blockIdx.x, r = blk >> 2, s = blk & 3, tid = threadIdx.x;
    for (int i = tid; i < NCOPY * HSTRIDE; i += 1024) lh[i] = 0.0f;
    float T = fmaxf(temps[r], 1e-5f), invT = 1.0f / T;
    float rm = -3.402823466e38f;
    for (int j = 0; j < 16; j++) rm = fmaxf(rm, smax[r * 16 + j]);
    float xm = rm * invT;
    float* myh = lh + (size_t)((tid & 3) * HSTRIDE);
    __syncthreads();
    const float4* L4 = (const float4*)(logits + (size_t)r * VV);
    int lo = s * K2SL4;

    auto proc = [&](float4 x) {
        float xs[4] = {x.x, x.y, x.z, x.w};
        #pragma unroll
        for (int k = 0; k < 4; k++) {
            float t = fmaf(xs[k], invT, -xm);
            if (t < -104.0f) continue;              // q bits would be exactly 0
            float q = __expf(t);
            u32 pb = __float_as_uint(q);
            if (pb) {
                int b = (int)(pb >> 18);
                if (b > HSTRIDE - 1) b = HSTRIDE - 1;   // can't fire (q<=~1.04); insurance
                atomicAdd(&myh[b], q);
            }
        }
    };

    // slice = 8000 float4, 1024 threads, positions tid + 1024k, k=0..7
    {
        int i0 = lo + tid;
        float4 a0 = L4[i0], a1 = L4[i0 + 1024], a2 = L4[i0 + 2048], a3 = L4[i0 + 3072];
        proc(a0); proc(a1); proc(a2); proc(a3);
        int i4 = i0 + 4096;
        float4 b0 = L4[i4], b1 = L4[i4 + 1024], b2 = L4[i4 + 2048];
        bool h3 = tid < (K2SL4 - 7 * 1024);         // tid < 832
        float4 b3;
        if (h3) b3 = L4[i4 + 3072];
        proc(b0); proc(b1); proc(b2);
        if (h3) proc(b3);
    }
    __syncthreads();
    float* gh = Whist + (size_t)r * NBUCK;
    // Merge ONLY i < HSTRIDE: buckets [4088,4096) are structurally empty and the
    // copy layout makes lh[i] for i>=HSTRIDE alias the next copy (R4's OOB bug).
    for (int i = tid; i < HSTRIDE; i += 1024) {
        float v = (lh[i] + lh[HSTRIDE + i]) + (lh[2 * HSTRIDE + i] + lh[3 * HSTRIDE + i]);
        if (v != 0.0f) atomicAdd(&gh[i], v);
    }
}

// ---------------- K3: per-row suffix scan + cut ----------------
extern "C" __global__ void __launch_bounds__(1024)
k3_cut(const float* __restrict__ Whist, const float* __restrict__ topps,
       RowPar* __restrict__ par) {
    int r = blockIdx.x, tid = threadIdx.x, lane = tid & 63, wid = tid >> 6;
    __shared__ double wtot[16];
    __shared__ double sh_cutZ; __shared__ int sh_b; __shared__ double sh_M;
    float4 h = ((const float4*)(Whist + (size_t)r * NBUCK))[tid];
    double s3 = (double)h.w, s2 = s3 + (double)h.z,
           s1 = s2 + (double)h.y, s0 = s1 + (double)h.x;
    double incl = s0;
    for (int off = 1; off < 64; off <<= 1) {
        double u = __shfl_down(incl, off);
        if (lane + off < 64) incl += u;
    }
    double excl = __shfl_down(incl, 1); if (lane == 63) excl = 0.0;
    if (lane == 0) wtot[wid] = incl;
    if (tid == 0) { sh_b = -1; sh_M = 0.0; }
    __syncthreads();
    double cw = 0.0;
    for (int w = wid + 1; w < 16; w++) cw += wtot[w];
    double carry = excl + cw;
    if (tid == 0) sh_cutZ = (double)topps[r] * (s0 + carry);
    __syncthreads();
    double cutZ = sh_cutZ;
    double S0 = s0 + carry, S1 = s1 + carry, S2 = s2 + carry, S3 = s3 + carry;
    if (S0 > cutZ && S1 <= cutZ)    { sh_b = 4 * tid;     sh_M = S1; }
    if (S1 > cutZ && S2 <= cutZ)    { sh_b = 4 * tid + 1; sh_M = S2; }
    if (S2 > cutZ && S3 <= cutZ)    { sh_b = 4 * tid + 2; sh_M = S3; }
    if (S3 > cutZ && carry <= cutZ) { sh_b = 4 * tid + 3; sh_M = carry; }
    __syncthreads();
    if (tid == 0) { RowPar p; p.bstar = sh_b; p.pad = 0; p.M = sh_M; p.cutZ = cutZ; par[r] = p; }
}

// ---------------- K4: per-slice race + crossing gather (4 loads in flight) ----
extern "C" __global__ void __launch_bounds__(256)
k4_race(const float* __restrict__ logits, const float* __restrict__ smax,
        const float* __restrict__ temps, const RowPar* __restrict__ par,
        int* __restrict__ Wcnt, u64* __restrict__ Wlist, u64* __restrict__ Wwin) {
    int blk = blockIdx.x, r = blk >> 4, s = blk & 15;
    int tid = threadIdx.x, lane = tid & 63, wid = tid >> 6;
    __shared__ u64 wred[4];
    float T = fmaxf(temps[r], 1e-5f), invT = 1.0f / T;
    float rm = -3.402823466e38f;
    for (int j = 0; j < 16; j++) rm = fmaxf(rm, smax[r * 16 + j]);
    float xm = rm * invT;
    int bstar = par[r].bstar;
    const float4* L4 = (const float4*)(logits + (size_t)r * VV);
    u32 jbase = (u32)r * (u32)VV;
    u64 pk = 0ULL;
    int lo = s * SL4;

    auto proc = [&](float4 x, int iv) {
        float xs[4] = {x.x, x.y, x.z, x.w};
        int base = iv * 4;
        #pragma unroll
        for (int k = 0; k < 4; k++) {
            float t = fmaf(xs[k], invT, -xm);
            if (t < -104.0f) continue;
            float q = __expf(t);
            u32 pb = __float_as_uint(q);
            if (!pb) continue;
            int b = (int)(pb >> 18);
            if (b > bstar) {
                u32 v = (u32)(base + k);
                float nz = noise_of(jbase + v);
                float sc = __fdividef(q, nz);
                u64 e = ((u64)__float_as_uint(sc) << 32) | (u64)(~v);
                if (e > pk) pk = e;
            } else if (b == bstar) {
                int pos = atomicAdd(&Wcnt[r], 1);
                if (pos < CAP)
                    Wlist[(size_t)r * CAP + pos] = ((u64)pb << 32) | (u64)(~(u32)(base + k));
            }
        }
    };

    // slice = 2000 float4, 256 threads, positions tid + 256k, k=0..7
    {
        int i0 = lo + tid;
        float4 a0 = L4[i0], a1 = L4[i0 + 256], a2 = L4[i0 + 512], a3 = L4[i0 + 768];
        proc(a0, i0); proc(a1, i0 + 256); proc(a2, i0 + 512); proc(a3, i0 + 768);
        int i4 = i0 + 1024;
        float4 b0 = L4[i4], b1 = L4[i4 + 256], b2 = L4[i4 + 512];
        bool h3 = tid < (SL4 - 7 * 256);            // tid < 208
        float4 b3;
        if (h3) b3 = L4[i4 + 768];
        proc(b0, i4); proc(b1, i4 + 256); proc(b2, i4 + 512);
        if (h3) proc(b3, i4 + 768);
    }
    for (int off = 32; off; off >>= 1) { u64 o = __shfl_down(pk, off); if (o > pk) pk = o; }
    if (lane == 0) wred[wid] = pk;
    __syncthreads();
    if (tid == 0) {
        for (int w = 1; w < 4; w++) if (wred[w] > pk) pk = wred[w];
        Wwin[blk] = pk;
    }
}

// ---------------- K5: per-row sort + exact cut + final race/merge ----------------
extern "C" __global__ void __launch_bounds__(1024)
k5_final(const float* __restrict__ smax, const int* __restrict__ sarg,
         const float* __restrict__ temps, const float* __restrict__ topps,
         const RowPar* __restrict__ par, const int* __restrict__ Wcnt,
         const u64* __restrict__ Wlist, const u64* __restrict__ Wwin,
         int* __restrict__ out) {
    int r = blockIdx.x, tid = threadIdx.x, lane = tid & 63, wid = tid >> 6;
    __shared__ u64 sb[CAP];
    __shared__ double wtot[16];
    __shared__ u64 wred[16];
    __shared__ int sh_js, sh_n, sh_gidx; __shared__ float sh_rm;
    RowPar p = par[r];
    if (tid == 0) {
        float rm = -3.402823466e38f; int gi = 0x7FFFFFFF;
        for (int j = 0; j < 16; j++) {
            float v = smax[r * 16 + j];
            if (v > rm) { rm = v; gi = sarg[r * 16 + j]; }
        }
        sh_rm = rm; sh_gidx = gi;
        int n = Wcnt[r]; if (n > CAP) n = CAP; sh_n = n;
        sh_js = 0x7FFFFFFF;
    }
    __syncthreads();
    int n = sh_n;
    int npad = 4; while (npad < n) npad <<= 1;
    const u64* lst = Wlist + (size_t)r * CAP;
    for (int i = tid; i < npad; i += 1024) sb[i] = (i < n) ? lst[i] : 0ULL;
    __syncthreads();
    for (int k = 2; k <= npad; k <<= 1) {
        for (int j = k >> 1; j > 0; j >>= 1) {
            for (int i = tid; i < npad; i += 1024) {
                int q2 = i ^ j;
                if (q2 > i) {
                    u64 a = sb[i], b = sb[q2];
                    bool desc = ((i & k) == 0);
                    if (desc ? (a < b) : (a > b)) { sb[i] = b; sb[q2] = a; }
                }
            }
            __syncthreads();
        }
    }
    int t2 = tid * 2;
    double f0 = 0.0, f1 = 0.0;
    if (t2 < npad) {
        f0 = (double)__uint_as_float((u32)(sb[t2] >> 32));
        f1 = (double)__uint_as_float((u32)(sb[t2 + 1] >> 32));
    }
    double c0 = f0, c1 = c0 + f1;
    double incl = c1;
    for (int off = 1; off < 64; off <<= 1) {
        double u = __shfl_up(incl, off);
        if (lane >= off) incl += u;
    }
    double excl = __shfl_up(incl, 1); if (lane == 0) excl = 0.0;
    double wt = __shfl(incl, 63);
    if (lane == 0) wtot[wid] = wt;
    __syncthreads();
    double cw = 0.0;
    for (int w = 0; w < wid; w++) cw += wtot[w];
    double cr = cw + excl;
    if (t2 < npad) {
        bool m0 = (p.M + (cr + c0)) > p.cutZ;
        bool m1 = (p.M + (cr + c1)) > p.cutZ;
        int cand = m0 ? t2 : m1 ? (t2 + 1) : 0x7FFFFFFF;
        if (cand != 0x7FFFFFFF) atomicMin(&sh_js, cand);
    }
    __syncthreads();
    float Traw = temps[r];
    if (tid == 0) {
        int js = sh_js; if (js > n) js = n;
        float T = fmaxf(Traw, 1e-5f), invT = 1.0f / T, xm = sh_rm * invT;
        int btop = (int)(__float_as_uint(q_of(sh_rm, invT, xm)) >> 18);
        if (js == 0 && p.bstar == btop) js = 1;   // mask[:,0]=False
        sh_js = js;
    }
    __syncthreads();
    int js = sh_js;
    u32 jbase = (u32)r * (u32)VV;
    u64 pk = 0ULL;
    for (int i = tid; i < js; i += 1024) {
        u64 key = sb[i];
        float qq = __uint_as_float((u32)(key >> 32));
        u32 v = ~(u32)key;
        float nz = noise_of(jbase + v);
        float sc = __fdividef(qq, nz);
        u64 e = ((u64)__float_as_uint(sc) << 32) | (u64)(~v);
        if (e > pk) pk = e;
    }
    if (tid < 16) { u64 w = Wwin[r * 16 + tid]; if (w > pk) pk = w; }
    for (int off = 32; off; off >>= 1) { u64 o = __shfl_down(pk, off); if (o > pk) pk = o; }
    if (lane == 0) wred[wid] = pk;
    __syncthreads();
    if (tid == 0) {
        for (int w = 1; w < 16; w++) if (wred[w] > pk) pk = wred[w];
        int bi = (int)(~(u32)pk);
        out[r] = (Traw <= 1e-10f) ? sh_gidx : bi;
    }
}

// ---------------- fallback: verified R2 monolithic kernel ----------------
extern "C" __global__ void __launch_bounds__(1024, 1)
sampler_fallback(const float* __restrict__ logits, const float* __restrict__ temps,
                 const float* __restrict__ topps, int* __restrict__ out)
{
    const int row = blockIdx.x;
    const int tid = threadIdx.x;
    const int lane = tid & 63;
    const int wid = tid >> 6;
    const float* L = logits + (size_t)row * VV;
    const float4* L4 = (const float4*)L;
    __shared__ __align__(16) unsigned char SMEM[32768];
    float* hist = (float*)SMEM;
    u64* sortbuf = (u64*)SMEM;
    __shared__ double wtot[16];
    __shared__ float wredf[16];
    __shared__ int wredi[16];
    __shared__ float sh_lmax;
    __shared__ int sh_gidx;
    __shared__ double sh_cutZ;
    __shared__ double sh_M;
    __shared__ int sh_bstar;
    __shared__ int sh_ng;
    __shared__ int sh_jstar;
    const float Traw = temps[row];
    const float T = fmaxf(Traw, 1e-5f);
    const float invT = 1.0f / T;
    const float tp = topps[row];
    float lmax = -3.402823466e38f; int lidx = 0x7FFFFFFF;
    for (int iv = tid; iv < NV4; iv += 1024) {
        float4 x = L4[iv];
        float m4 = fmaxf(fmaxf(x.x, x.y), fmaxf(x.z, x.w));
        if (m4 > lmax) {
            int base = iv * 4;
            if      (x.x == m4) lidx = base;
            else if (x.y == m4) lidx = base + 1;
            else if (x.z == m4) lidx = base + 2;
            else                lidx = base + 3;
            lmax = m4;
        }
    }
    for (int off = 32; off > 0; off >>= 1) {
        float ov = __shfl_down(lmax, off);
        int   oi = __shfl_down(lidx, off);
        if (ov > lmax || (ov == lmax && oi < lidx)) { lmax = ov; lidx = oi; }
    }
    if (lane == 0) { wredf[wid] = lmax; wredi[wid] = lidx; }
    for (int i = tid; i < NBUCK; i += 1024) hist[i] = 0.0f;
    __syncthreads();
    if (wid == 0) {
        float v = (lane < 16) ? wredf[lane] : -3.402823466e38f;
        int   i = (lane < 16) ? wredi[lane] : 0x7FFFFFFF;
        for (int off = 32; off > 0; off >>= 1) {
            float ov = __shfl_down(v, off);
            int   oi = __shfl_down(i, off);
            if (ov > v || (ov == v && oi < i)) { v = ov; i = oi; }
        }
        if (lane == 0) { sh_lmax = v; sh_gidx = i; }
    }
    __syncthreads();
    const float xm = sh_lmax * invT;
    const int gidx = sh_gidx;
    const int btop = (int)(__float_as_uint(q_of(sh_lmax, invT, xm)) >> 18);
    for (int iv = tid; iv < NV4; iv += 1024) {
        float4 x = L4[iv];
        float q0 = q_of(x.x, invT, xm), q1 = q_of(x.y, invT, xm);
        float q2 = q_of(x.z, invT, xm), q3 = q_of(x.w, invT, xm);
        u32 b0 = __float_as_uint(q0), b1 = __float_as_uint(q1);
        u32 b2 = __float_as_uint(q2), b3 = __float_as_uint(q3);
        if (b0) atomicAdd(&hist[b0 >> 18], q0);
        if (b1) atomicAdd(&hist[b1 >> 18], q1);
        if (b2) atomicAdd(&hist[b2 >> 18], q2);
        if (b3) atomicAdd(&hist[b3 >> 18], q3);
    }
    __syncthreads();
    float h0 = hist[4 * tid], h1 = hist[4 * tid + 1],
          h2 = hist[4 * tid + 2], h3 = hist[4 * tid + 3];
    double s3 = (double)h3, s2 = s3 + (double)h2, s1 = s2 + (double)h1, s0 = s1 + (double)h0;
    double incl = s0;
    for (int off = 1; off < 64; off <<= 1) {
        double u = __shfl_down(incl, off);
        if (lane + off < 64) incl += u;
    }
    double excl = __shfl_down(incl, 1);
    if (lane == 63) excl = 0.0;
    if (lane == 0) wtot[wid] = incl;
    __syncthreads();
    double cw = 0.0;
    for (int w = wid + 1; w < 16; w++) cw += wtot[w];
    const double carry = excl + cw;
    if (tid == 0) {
        sh_cutZ = (double)tp * (s0 + carry);
        sh_bstar = -1; sh_M = 0.0; sh_ng = 0; sh_jstar = 0x7FFFFFFF;
    }
    __syncthreads();
    const double cutZ = sh_cutZ;
    {
        double S0 = s0 + carry, S1 = s1 + carry, S2 = s2 + carry, S3 = s3 + carry;
        if (S0 > cutZ && S1 <= cutZ)    { sh_bstar = 4 * tid;     sh_M = S1; }
        if (S1 > cutZ && S2 <= cutZ)    { sh_bstar = 4 * tid + 1; sh_M = S2; }
        if (S2 > cutZ && S3 <= cutZ)    { sh_bstar = 4 * tid + 2; sh_M = S3; }
        if (S3 > cutZ && carry <= cutZ) { sh_bstar = 4 * tid + 3; sh_M = carry; }
    }
    __syncthreads();
    const int bstar = sh_bstar;
    const double M = sh_M;
    float bs = -1.0f; int bi = 0x7FFFFFFF;
    const u32 jbase = (u32)row * (u32)VV;
    for (int iv = tid; iv < NV4; iv += 1024) {
        float4 x = L4[iv];
        float qs[4] = {q_of(x.x, invT, xm), q_of(x.y, invT, xm),
                       q_of(x.z, invT, xm), q_of(x.w, invT, xm)};
        int base = iv * 4;
        #pragma unroll
        for (int k = 0; k < 4; k++) {
            u32 pb = __float_as_uint(qs[k]);
            if (pb == 0u) continue;
            int b = (int)(pb >> 18);
            if (b > bstar) {
                int v = base + k;
                float nz = noise_of(jbase + (u32)v);
                float sc = __fdividef(qs[k], nz);
                if (sc > bs || (sc == bs && v < bi)) { bs = sc; bi = v; }
            } else if (b == bstar) {
                int pos = atomicAdd(&sh_ng, 1);
                if (pos < 4096)
                    sortbuf[pos] = ((u64)pb << 32) | (u32)(~(u32)(base + k));
            }
        }
    }
    __syncthreads();
    if (bstar >= 0) {
        int n = sh_ng; if (n > 4096) n = 4096;
        int npad = 4; while (npad < n) npad <<= 1;
        for (int i = tid; i < npad; i += 1024) if (i >= n) sortbuf[i] = 0ULL;
        __syncthreads();
        for (int k = 2; k <= npad; k <<= 1) {
            for (int j = k >> 1; j > 0; j >>= 1) {
                for (int i = tid; i < npad; i += 1024) {
                    int pidx = i ^ j;
                    if (pidx > i) {
                        u64 a = sortbuf[i], b2 = sortbuf[pidx];
                        bool desc = ((i & k) == 0);
                        if (desc ? (a < b2) : (a > b2)) { sortbuf[i] = b2; sortbuf[pidx] = a; }
                    }
                }
                __syncthreads();
            }
        }
        double f0 = 0.0, f1 = 0.0, f2 = 0.0, f3 = 0.0;
        int t4 = tid * 4;
        if (t4 < npad) {
            f0 = (double)__uint_as_float((u32)(sortbuf[t4]     >> 32));
            f1 = (double)__uint_as_float((u32)(sortbuf[t4 + 1] >> 32));
            f2 = (double)__uint_as_float((u32)(sortbuf[t4 + 2] >> 32));
            f3 = (double)__uint_as_float((u32)(sortbuf[t4 + 3] >> 32));
        }
        double c0 = f0, c1 = c0 + f1, c2 = c1 + f2, c3 = c2 + f3;
        double incl2 = c3;
        for (int off = 1; off < 64; off <<= 1) {
            double u = __shfl_up(incl2, off);
            if (lane >= off) incl2 += u;
        }
        double excl2 = __shfl_up(incl2, 1);
        if (lane == 0) excl2 = 0.0;
        double wt = __shfl(incl2, 63);
        if (lane == 0) wtot[wid] = wt;
        __syncthreads();
        double cw2 = 0.0;
        for (int w = 0; w < wid; w++) cw2 += wtot[w];
        double cr = cw2 + excl2;
        if (t4 < npad) {
            bool m0 = (M + (cr + c0)) > cutZ;
            bool m1 = (M + (cr + c1)) > cutZ;
            bool m2 = (M + (cr + c2)) > cutZ;
            bool m3 = (M + (cr + c3)) > cutZ;
            int cand = m0 ? t4 : m1 ? (t4 + 1) : m2 ? (t4 + 2) : m3 ? (t4 + 3) : 0x7FFFFFFF;
            if (cand != 0x7FFFFFFF) atomicMin(&sh_jstar, cand);
        }
        __syncthreads();
        int jstar = sh_jstar; if (jstar > n) jstar = n;
        if (jstar == 0 && bstar == btop) jstar = 1;
        for (int i = tid; i < jstar; i += 1024) {
            u64 key = sortbuf[i];
            float qq = __uint_as_float((u32)(key >> 32));
            int v = (int)(~(u32)key);
            float nz = noise_of(jbase + (u32)v);
            float sc = __fdividef(qq, nz);
            if (sc > bs || (sc == bs && v < bi)) { bs = sc; bi = v; }
        }
    }
    for (int off = 32; off > 0; off >>= 1) {
        float ov = __shfl_down(bs, off);
        int   oi = __shfl_down(bi, off);
        if (ov > bs || (ov == bs && oi < bi)) { bs = ov; bi = oi; }
    }
    if (lane == 0) { wredf[wid] = bs; wredi[wid] = bi; }
    __syncthreads();
    if (tid == 0) {
        float v = wredf[0]; int i = wredi[0];
        for (int w = 1; w < 16; w++) {
            float ov = wredf[w]; int oi = wredi[w];
            if (ov > v || (ov == v && oi < i)) { v = ov; i = oi; }
        }
        out[row] = (Traw <= 1e-10f) ? gidx : i;
    }
}

extern "C" void kernel_launch(void* const* d_in, const int* in_sizes, int n_in,
                              void* d_out, int out_size, void* d_ws, size_t ws_size,
                              hipStream_t stream) {
    const float* logits = (const float*)d_in[0];
    const float* temps = (const float*)d_in[1];
    const float* topps = (const float*)d_in[2];
    int* out = (int*)d_out;
    (void)in_sizes; (void)n_in; (void)out_size;

    if (ws_size >= WS_TOTAL) {
        char* ws = (char*)d_ws;
        float* smax  = (float*)(ws + OFF_SMAX);
        int*   sarg  = (int*)(ws + OFF_SARG);
        u64*   wwin  = (u64*)(ws + OFF_WWIN);
        RowPar* par  = (RowPar*)(ws + OFF_PAR);
        int*   wcnt  = (int*)(ws + OFF_CNT);
        float* whist = (float*)(ws + OFF_HIST);
        u64*   wlist = (u64*)(ws + OFF_LIST);
        hipMemsetAsync(wcnt, 0, BB * sizeof(int), stream);
        hipMemsetAsync(whist, 0, (size_t)BB * NBUCK * sizeof(float), stream);
        k1_stats<<<BB * SLICES, 256, 0, stream>>>(logits, smax, sarg);
        k2_hist<<<BB * K2S, 1024, 0, stream>>>(logits, smax, temps, whist);
        k3_cut<<<BB, 1024, 0, stream>>>(whist, topps, par);
        k4_race<<<BB * SLICES, 256, 0, stream>>>(logits, smax, temps, par, wcnt, wlist, wwin);
        k5_final<<<BB, 1024, 0, stream>>>(smax, sarg, temps, topps, par, wcnt, wlist, wwin, out);
    } else {
        sampler_fallback<<<BB, 1024, 0, stream>>>(logits, temps, topps, out);
    }
}

// Round 6
// 386.895 us; speedup vs baseline: 1.8460x; 1.3649x over previous
//
#include <hip/hip_runtime.h>
#include <stdint.h>

typedef unsigned long long u64;
typedef uint32_t u32;

#define BB 256
#define VV 128000
#define NV4 (VV / 4)          // 32000 float4 per row
#define SLICES 16
#define SL4 (NV4 / SLICES)    // 2000 float4 per slice
#define NBUCK 4096
#define CAP 2048
#define QSCALE 1.099511627776e12f   // 2^40 fixed-point scale for q
#define QINV   (1.0 / 1099511627776.0)

// ---- workspace layout (bytes) ----
#define OFF_SMAX 0                          // float[256*16]
#define OFF_SARG (16*1024)                  // int[256*16]
#define OFF_WWIN (32*1024)                  // u64[256*16]
#define OFF_PAR  (64*1024)                  // RowPar[256]
#define OFF_CNT  (72*1024)                  // int[256]   (zeroed by k1)
#define OFF_HIST (80*1024)                  // u64[256*4096] (zeroed by k1)
#define OFF_LIST (OFF_HIST + (size_t)BB*NBUCK*8)  // u64[256*CAP]
#define WS_TOTAL (OFF_LIST + (size_t)BB*CAP*8)

struct RowPar { int bstar; float thr; double M; double cutZ; };

#if defined(__has_builtin)
# if __has_builtin(__builtin_amdgcn_sched_barrier)
#  define SCHED_FENCE() __builtin_amdgcn_sched_barrier(0)
# endif
#endif
#ifndef SCHED_FENCE
# define SCHED_FENCE() asm volatile("" ::: "memory")
#endif

__device__ __forceinline__ u32 rotl32(u32 v, u32 r) { return (v << r) | (v >> (32u - r)); }

// JAX partitionable threefry, key=(0,1), ctr=(0,j), bits=o0^o1.
// Verified bit-exact (R1-R5 absmax 0). DO NOT TOUCH.
__device__ __forceinline__ u32 threefry_bits(u32 j) {
    const u32 ks0 = 0u, ks1 = 1u, ks2 = 0x1BD11BDBu;
    u32 x0 = ks0, x1 = j + ks1;
    x0 += x1; x1 = rotl32(x1, 13); x1 ^= x0;
    x0 += x1; x1 = rotl32(x1, 15); x1 ^= x0;
    x0 += x1; x1 = rotl32(x1, 26); x1 ^= x0;
    x0 += x1; x1 = rotl32(x1, 6);  x1 ^= x0;
    x0 += ks1; x1 += ks2 + 1u;
    x0 += x1; x1 = rotl32(x1, 17); x1 ^= x0;
    x0 += x1; x1 = rotl32(x1, 29); x1 ^= x0;
    x0 += x1; x1 = rotl32(x1, 16); x1 ^= x0;
    x0 += x1; x1 = rotl32(x1, 24); x1 ^= x0;
    x0 += ks2; x1 += ks0 + 2u;
    x0 += x1; x1 = rotl32(x1, 13); x1 ^= x0;
    x0 += x1; x1 = rotl32(x1, 15); x1 ^= x0;
    x0 += x1; x1 = rotl32(x1, 26); x1 ^= x0;
    x0 += x1; x1 = rotl32(x1, 6);  x1 ^= x0;
    x0 += ks0; x1 += ks1 + 3u;
    x0 += x1; x1 = rotl32(x1, 17); x1 ^= x0;
    x0 += x1; x1 = rotl32(x1, 29); x1 ^= x0;
    x0 += x1; x1 = rotl32(x1, 16); x1 ^= x0;
    x0 += x1; x1 = rotl32(x1, 24); x1 ^= x0;
    x0 += ks1; x1 += ks2 + 4u;
    x0 += x1; x1 = rotl32(x1, 13); x1 ^= x0;
    x0 += x1; x1 = rotl32(x1, 15); x1 ^= x0;
    x0 += x1; x1 = rotl32(x1, 26); x1 ^= x0;
    x0 += x1; x1 = rotl32(x1, 6);  x1 ^= x0;
    x0 += ks2; x1 += ks0 + 5u;
    return x0 ^ x1;
}

__device__ __forceinline__ float q_of(float x, float invT, float xm) {
    return __expf(fmaf(x, invT, -xm));
}

__device__ __forceinline__ float noise_of(u32 j) {
    u32 bits = threefry_bits(j);
    float u = __uint_as_float((bits >> 9) | 0x3F800000u) - 1.0f;
    return fmaxf(-log1pf(-u), 1e-10f);
}

// ---------------- K1: per-slice max/argmax + workspace zeroing ----------------
extern "C" __global__ void __launch_bounds__(256, 1)
k1_stats(const float* __restrict__ logits, float* __restrict__ smax,
         int* __restrict__ sarg, u64* __restrict__ Whist, int* __restrict__ Wcnt) {
    int blk = blockIdx.x, r = blk >> 4, s = blk & 15;
    int tid = threadIdx.x, lane = tid & 63, wid = tid >> 6;
    __shared__ float sf[4]; __shared__ int si[4];
    // zero this slice's chunk of the row hist + counter (replaces memsets)
    Whist[(size_t)r * NBUCK + s * 256 + tid] = 0ULL;
    if (s == 0 && tid == 0) Wcnt[r] = 0;
    const float4* L4 = (const float4*)(logits + (size_t)r * VV);
    int i0 = s * SL4 + tid;
    bool h7 = tid < (SL4 - 7 * 256);   // tid < 208
    float4 b0 = L4[i0],          b1 = L4[i0 + 256],  b2 = L4[i0 + 512];
    float4 b3 = L4[i0 + 768],    b4 = L4[i0 + 1024], b5 = L4[i0 + 1280];
    float4 b6 = L4[i0 + 1536],   b7 = L4[h7 ? i0 + 1792 : i0];
    SCHED_FENCE();                      // keep all 8 loads in flight (MLP=8)
    float m = -3.402823466e38f; int mi = 0x7FFFFFFF;
    auto upd = [&](float4 a, int iv) {
        float m4 = fmaxf(fmaxf(a.x, a.y), fmaxf(a.z, a.w));
        if (m4 > m) {                   // strict > keeps first occurrence
            int base = iv * 4;
            if      (a.x == m4) mi = base;
            else if (a.y == m4) mi = base + 1;
            else if (a.z == m4) mi = base + 2;
            else                mi = base + 3;
            m = m4;
        }
    };
    upd(b0, i0);        upd(b1, i0 + 256);  upd(b2, i0 + 512);  upd(b3, i0 + 768);
    upd(b4, i0 + 1024); upd(b5, i0 + 1280); upd(b6, i0 + 1536);
    if (h7) upd(b7, i0 + 1792);
    for (int off = 32; off; off >>= 1) {
        float ov = __shfl_down(m, off); int oi = __shfl_down(mi, off);
        if (ov > m || (ov == m && oi < mi)) { m = ov; mi = oi; }
    }
    if (lane == 0) { sf[wid] = m; si[wid] = mi; }
    __syncthreads();
    if (tid == 0) {
        for (int w = 1; w < 4; w++) {
            float ov = sf[w]; int oi = si[w];
            if (ov > m || (ov == m && oi < mi)) { m = ov; mi = oi; }
        }
        smax[blk] = m; sarg[blk] = mi;
    }
}

// -------- K2: u64 fixed-point LDS histogram (fast integer DS atomics) --------
extern "C" __global__ void __launch_bounds__(256, 1)
k2_hist(const float* __restrict__ logits, const float* __restrict__ smax,
        const float* __restrict__ temps, u64* __restrict__ Whist) {
    __shared__ u64 lh[NBUCK];           // 32 KB
    int blk = blockIdx.x, r = blk >> 4, s = blk & 15, tid = threadIdx.x;
    for (int i = tid; i < NBUCK; i += 256) lh[i] = 0ULL;
    float T = fmaxf(temps[r], 1e-5f), invT = 1.0f / T;
    float rm = -3.402823466e38f;
    for (int j = 0; j < 16; j++) rm = fmaxf(rm, smax[r * 16 + j]);
    float xm = rm * invT;
    __syncthreads();
    const float4* L4 = (const float4*)(logits + (size_t)r * VV);
    int i0 = s * SL4 + tid;
    bool h7 = tid < (SL4 - 7 * 256);
    float4 b0 = L4[i0],          b1 = L4[i0 + 256],  b2 = L4[i0 + 512];
    float4 b3 = L4[i0 + 768],    b4 = L4[i0 + 1024], b5 = L4[i0 + 1280];
    float4 b6 = L4[i0 + 1536],   b7 = L4[h7 ? i0 + 1792 : i0];
    SCHED_FENCE();
    auto proc = [&](float4 x) {
        float xs[4] = {x.x, x.y, x.z, x.w};
        #pragma unroll
        for (int k = 0; k < 4; k++) {
            float t = fmaf(xs[k], invT, -xm);
            if (t < -104.0f) continue;          // q bits would be exactly 0
            float q = __expf(t);
            u32 pb = __float_as_uint(q);
            if (pb) atomicAdd(&lh[pb >> 18], (u64)(q * QSCALE));
        }
    };
    proc(b0); proc(b1); proc(b2); proc(b3); proc(b4); proc(b5); proc(b6);
    if (h7) proc(b7);
    __syncthreads();
    u64* gh = Whist + (size_t)r * NBUCK;
    for (int i = tid; i < NBUCK; i += 256) {
        u64 v = lh[i];
        if (v) atomicAdd(&gh[i], v);
    }
}

// ---------------- K3: per-row suffix scan + cut + skip-threshold ----------------
extern "C" __global__ void __launch_bounds__(1024)
k3_cut(const u64* __restrict__ Whist, const float* __restrict__ topps,
       RowPar* __restrict__ par) {
    int r = blockIdx.x, tid = threadIdx.x, lane = tid & 63, wid = tid >> 6;
    __shared__ double wtot[16];
    __shared__ double sh_cutZ; __shared__ int sh_b; __shared__ double sh_M;
    const u64* gh = Whist + (size_t)r * NBUCK;
    double h0 = (double)gh[4 * tid]     * QINV;
    double h1 = (double)gh[4 * tid + 1] * QINV;
    double h2 = (double)gh[4 * tid + 2] * QINV;
    double h3 = (double)gh[4 * tid + 3] * QINV;
    double s3 = h3, s2 = s3 + h2, s1 = s2 + h1, s0 = s1 + h0;
    double incl = s0;
    for (int off = 1; off < 64; off <<= 1) {
        double u = __shfl_down(incl, off);
        if (lane + off < 64) incl += u;
    }
    double excl = __shfl_down(incl, 1); if (lane == 63) excl = 0.0;
    if (lane == 0) wtot[wid] = incl;
    if (tid == 0) { sh_b = -1; sh_M = 0.0; }
    __syncthreads();
    double cw = 0.0;
    for (int w = wid + 1; w < 16; w++) cw += wtot[w];
    double carry = excl + cw;
    if (tid == 0) sh_cutZ = (double)topps[r] * (s0 + carry);
    __syncthreads();
    double cutZ = sh_cutZ;
    double S0 = s0 + carry, S1 = s1 + carry, S2 = s2 + carry, S3 = s3 + carry;
    if (S0 > cutZ && S1 <= cutZ)    { sh_b = 4 * tid;     sh_M = S1; }
    if (S1 > cutZ && S2 <= cutZ)    { sh_b = 4 * tid + 1; sh_M = S2; }
    if (S2 > cutZ && S3 <= cutZ)    { sh_b = 4 * tid + 2; sh_M = S3; }
    if (S3 > cutZ && carry <= cutZ) { sh_b = 4 * tid + 3; sh_M = carry; }
    __syncthreads();
    if (tid == 0) {
        // conservative t-threshold: bucket(q_of(t)) >= bstar  =>  t >= thr
        float thr = -3.402823466e38f;
        if (sh_b > 0) {
            float qlo = __uint_as_float((u32)sh_b << 18);
            if (qlo >= 1.17549435e-38f) thr = logf(qlo) - 1e-3f;
        }
        RowPar p; p.bstar = sh_b; p.thr = thr; p.M = sh_M; p.cutZ = cutZ;
        par[r] = p;
    }
}

// -------- K4: per-slice race + crossing gather (thr prefilter, MLP=8) --------
extern "C" __global__ void __launch_bounds__(256, 1)
k4_race(const float* __restrict__ logits, const float* __restrict__ smax,
        const float* __restrict__ temps, const RowPar* __restrict__ par,
        int* __restrict__ Wcnt, u64* __restrict__ Wlist, u64* __restrict__ Wwin) {
    int blk = blockIdx.x, r = blk >> 4, s = blk & 15;
    int tid = threadIdx.x, lane = tid & 63, wid = tid >> 6;
    __shared__ u64 wred[4];
    float T = fmaxf(temps[r], 1e-5f), invT = 1.0f / T;
    float rm = -3.402823466e38f;
    for (int j = 0; j < 16; j++) rm = fmaxf(rm, smax[r * 16 + j]);
    float xm = rm * invT;
    int bstar = par[r].bstar;
    float thr = par[r].thr;
    const float4* L4 = (const float4*)(logits + (size_t)r * VV);
    u32 jbase = (u32)r * (u32)VV;
    u64 pk = 0ULL;
    int i0 = s * SL4 + tid;
    bool h7 = tid < (SL4 - 7 * 256);
    float4 b0 = L4[i0],          b1 = L4[i0 + 256],  b2 = L4[i0 + 512];
    float4 b3 = L4[i0 + 768],    b4 = L4[i0 + 1024], b5 = L4[i0 + 1280];
    float4 b6 = L4[i0 + 1536],   b7 = L4[h7 ? i0 + 1792 : i0];
    SCHED_FENCE();
    auto proc = [&](float4 x, int iv) {
        float xs[4] = {x.x, x.y, x.z, x.w};
        int base = iv * 4;
        #pragma unroll
        for (int k = 0; k < 4; k++) {
            float t = fmaf(xs[k], invT, -xm);
            if (t < thr) continue;              // provably below bucket b*
            float q = __expf(t);
            u32 pb = __float_as_uint(q);
            if (!pb) continue;
            int b = (int)(pb >> 18);
            if (b > bstar) {
                u32 v = (u32)(base + k);
                float nz = noise_of(jbase + v);
                float sc = __fdividef(q, nz);
                u64 e = ((u64)__float_as_uint(sc) << 32) | (u64)(~v);
                if (e > pk) pk = e;
            } else if (b == bstar) {
                int pos = atomicAdd(&Wcnt[r], 1);
                if (pos < CAP)
                    Wlist[(size_t)r * CAP + pos] = ((u64)pb << 32) | (u64)(~(u32)(base + k));
            }
        }
    };
    proc(b0, i0);        proc(b1, i0 + 256);  proc(b2, i0 + 512);  proc(b3, i0 + 768);
    proc(b4, i0 + 1024); proc(b5, i0 + 1280); proc(b6, i0 + 1536);
    if (h7) proc(b7, i0 + 1792);
    for (int off = 32; off; off >>= 1) { u64 o = __shfl_down(pk, off); if (o > pk) pk = o; }
    if (lane == 0) wred[wid] = pk;
    __syncthreads();
    if (tid == 0) {
        for (int w = 1; w < 4; w++) if (wred[w] > pk) pk = wred[w];
        Wwin[blk] = pk;
    }
}

// ---------------- K5: per-row sort + exact cut + final race/merge ----------------
extern "C" __global__ void __launch_bounds__(1024)
k5_final(const float* __restrict__ smax, const int* __restrict__ sarg,
         const float* __restrict__ temps, const float* __restrict__ topps,
         const RowPar* __restrict__ par, const int* __restrict__ Wcnt,
         const u64* __restrict__ Wlist, const u64* __restrict__ Wwin,
         int* __restrict__ out) {
    int r = blockIdx.x, tid = threadIdx.x, lane = tid & 63, wid = tid >> 6;
    __shared__ u64 sb[CAP];
    __shared__ double wtot[16];
    __shared__ u64 wred[16];
    __shared__ int sh_js, sh_n, sh_gidx; __shared__ float sh_rm;
    RowPar p = par[r];
    if (tid == 0) {
        float rm = -3.402823466e38f; int gi = 0x7FFFFFFF;
        for (int j = 0; j < 16; j++) {
            float v = smax[r * 16 + j];
            if (v > rm) { rm = v; gi = sarg[r * 16 + j]; }
        }
        sh_rm = rm; sh_gidx = gi;
        int n = Wcnt[r]; if (n > CAP) n = CAP; sh_n = n;
        sh_js = 0x7FFFFFFF;
    }
    __syncthreads();
    int n = sh_n;
    int npad = 4; while (npad < n) npad <<= 1;
    const u64* lst = Wlist + (size_t)r * CAP;
    for (int i = tid; i < npad; i += 1024) sb[i] = (i < n) ? lst[i] : 0ULL;
    __syncthreads();
    for (int k = 2; k <= npad; k <<= 1) {
        for (int j = k >> 1; j > 0; j >>= 1) {
            for (int i = tid; i < npad; i += 1024) {
                int q2 = i ^ j;
                if (q2 > i) {
                    u64 a = sb[i], b = sb[q2];
                    bool desc = ((i & k) == 0);
                    if (desc ? (a < b) : (a > b)) { sb[i] = b; sb[q2] = a; }
                }
            }
            __syncthreads();
        }
    }
    int t2 = tid * 2;
    double f0 = 0.0, f1 = 0.0;
    if (t2 < npad) {
        f0 = (double)__uint_as_float((u32)(sb[t2] >> 32));
        f1 = (double)__uint_as_float((u32)(sb[t2 + 1] >> 32));
    }
    double c0 = f0, c1 = c0 + f1;
    double incl = c1;
    for (int off = 1; off < 64; off <<= 1) {
        double u = __shfl_up(incl, off);
        if (lane >= off) incl += u;
    }
    double excl = __shfl_up(incl, 1); if (lane == 0) excl = 0.0;
    double wt = __shfl(incl, 63);
    if (lane == 0) wtot[wid] = wt;
    __syncthreads();
    double cw = 0.0;
    for (int w = 0; w < wid; w++) cw += wtot[w];
    double cr = cw + excl;
    if (t2 < npad) {
        bool m0 = (p.M + (cr + c0)) > p.cutZ;
        bool m1 = (p.M + (cr + c1)) > p.cutZ;
        int cand = m0 ? t2 : m1 ? (t2 + 1) : 0x7FFFFFFF;
        if (cand != 0x7FFFFFFF) atomicMin(&sh_js, cand);
    }
    __syncthreads();
    float Traw = temps[r];
    if (tid == 0) {
        int js = sh_js; if (js > n) js = n;
        float T = fmaxf(Traw, 1e-5f), invT = 1.0f / T, xm = sh_rm * invT;
        int btop = (int)(__float_as_uint(q_of(sh_rm, invT, xm)) >> 18);
        if (js == 0 && p.bstar == btop) js = 1;   // mask[:,0]=False
        sh_js = js;
    }
    __syncthreads();
    int js = sh_js;
    u32 jbase = (u32)r * (u32)VV;
    u64 pk = 0ULL;
    for (int i = tid; i < js; i += 1024) {
        u64 key = sb[i];
        float qq = __uint_as_float((u32)(key >> 32));
        u32 v = ~(u32)key;
        float nz = noise_of(jbase + v);
        float sc = __fdividef(qq, nz);
        u64 e = ((u64)__float_as_uint(sc) << 32) | (u64)(~v);
        if (e > pk) pk = e;
    }
    if (tid < 16) { u64 w = Wwin[r * 16 + tid]; if (w > pk) pk = w; }
    for (int off = 32; off; off >>= 1) { u64 o = __shfl_down(pk, off); if (o > pk) pk = o; }
    if (lane == 0) wred[wid] = pk;
    __syncthreads();
    if (tid == 0) {
        for (int w = 1; w < 16; w++) if (wred[w] > pk) pk = wred[w];
        int bi = (int)(~(u32)pk);
        out[r] = (Traw <= 1e-10f) ? sh_gidx : bi;
    }
}

// ---------------- fallback: verified R2 monolithic kernel ----------------
extern "C" __global__ void __launch_bounds__(1024, 1)
sampler_fallback(const float* __restrict__ logits, const float* __restrict__ temps,
                 const float* __restrict__ topps, int* __restrict__ out)
{
    const int row = blockIdx.x;
    const int tid = threadIdx.x;
    const int lane = tid & 63;
    const int wid = tid >> 6;
    const float* L = logits + (size_t)row * VV;
    const float4* L4 = (const float4*)L;
    __shared__ __align__(16) unsigned char SMEM[32768];
    float* hist = (float*)SMEM;
    u64* sortbuf = (u64*)SMEM;
    __shared__ double wtot[16];
    __shared__ float wredf[16];
    __shared__ int wredi[16];
    __shared__ float sh_lmax;
    __shared__ int sh_gidx;
    __shared__ double sh_cutZ;
    __shared__ double sh_M;
    __shared__ int sh_bstar;
    __shared__ int sh_ng;
    __shared__ int sh_jstar;
    const float Traw = temps[row];
    const float T = fmaxf(Traw, 1e-5f);
    const float invT = 1.0f / T;
    const float tp = topps[row];
    float lmax = -3.402823466e38f; int lidx = 0x7FFFFFFF;
    for (int iv = tid; iv < NV4; iv += 1024) {
        float4 x = L4[iv];
        float m4 = fmaxf(fmaxf(x.x, x.y), fmaxf(x.z, x.w));
        if (m4 > lmax) {
            int base = iv * 4;
            if      (x.x == m4) lidx = base;
            else if (x.y == m4) lidx = base + 1;
            else if (x.z == m4) lidx = base + 2;
            else                lidx = base + 3;
            lmax = m4;
        }
    }
    for (int off = 32; off > 0; off >>= 1) {
        float ov = __shfl_down(lmax, off);
        int   oi = __shfl_down(lidx, off);
        if (ov > lmax || (ov == lmax && oi < lidx)) { lmax = ov; lidx = oi; }
    }
    if (lane == 0) { wredf[wid] = lmax; wredi[wid] = lidx; }
    for (int i = tid; i < NBUCK; i += 1024) hist[i] = 0.0f;
    __syncthreads();
    if (wid == 0) {
        float v = (lane < 16) ? wredf[lane] : -3.402823466e38f;
        int   i = (lane < 16) ? wredi[lane] : 0x7FFFFFFF;
        for (int off = 32; off > 0; off >>= 1) {
            float ov = __shfl_down(v, off);
            int   oi = __shfl_down(i, off);
            if (ov > v || (ov == v && oi < i)) { v = ov; i = oi; }
        }
        if (lane == 0) { sh_lmax = v; sh_gidx = i; }
    }
    __syncthreads();
    const float xm = sh_lmax * invT;
    const int gidx = sh_gidx;
    const int btop = (int)(__float_as_uint(q_of(sh_lmax, invT, xm)) >> 18);
    for (int iv = tid; iv < NV4; iv += 1024) {
        float4 x = L4[iv];
        float q0 = q_of(x.x, invT, xm), q1 = q_of(x.y, invT, xm);
        float q2 = q_of(x.z, invT, xm), q3 = q_of(x.w, invT, xm);
        u32 b0 = __float_as_uint(q0), b1 = __float_as_uint(q1);
        u32 b2 = __float_as_uint(q2), b3 = __float_as_uint(q3);
        if (b0) atomicAdd(&hist[b0 >> 18], q0);
        if (b1) atomicAdd(&hist[b1 >> 18], q1);
        if (b2) atomicAdd(&hist[b2 >> 18], q2);
        if (b3) atomicAdd(&hist[b3 >> 18], q3);
    }
    __syncthreads();
    float h0 = hist[4 * tid], h1 = hist[4 * tid + 1],
          h2 = hist[4 * tid + 2], h3 = hist[4 * tid + 3];
    double s3 = (double)h3, s2 = s3 + (double)h2, s1 = s2 + (double)h1, s0 = s1 + (double)h0;
    double incl = s0;
    for (int off = 1; off < 64; off <<= 1) {
        double u = __shfl_down(incl, off);
        if (lane + off < 64) incl += u;
    }
    double excl = __shfl_down(incl, 1);
    if (lane == 63) excl = 0.0;
    if (lane == 0) wtot[wid] = incl;
    __syncthreads();
    double cw = 0.0;
    for (int w = wid + 1; w < 16; w++) cw += wtot[w];
    const double carry = excl + cw;
    if (tid == 0) {
        sh_cutZ = (double)tp * (s0 + carry);
        sh_bstar = -1; sh_M = 0.0; sh_ng = 0; sh_jstar = 0x7FFFFFFF;
    }
    __syncthreads();
    const double cutZ = sh_cutZ;
    {
        double S0 = s0 + carry, S1 = s1 + carry, S2 = s2 + carry, S3 = s3 + carry;
        if (S0 > cutZ && S1 <= cutZ)    { sh_bstar = 4 * tid;     sh_M = S1; }
        if (S1 > cutZ && S2 <= cutZ)    { sh_bstar = 4 * tid + 1; sh_M = S2; }
        if (S2 > cutZ && S3 <= cutZ)    { sh_bstar = 4 * tid + 2; sh_M = S3; }
        if (S3 > cutZ && carry <= cutZ) { sh_bstar = 4 * tid + 3; sh_M = carry; }
    }
    __syncthreads();
    const int bstar = sh_bstar;
    const double M = sh_M;
    float bs = -1.0f; int bi = 0x7FFFFFFF;
    const u32 jbase = (u32)row * (u32)VV;
    for (int iv = tid; iv < NV4; iv += 1024) {
        float4 x = L4[iv];
        float qs[4] = {q_of(x.x, invT, xm), q_of(x.y, invT, xm),
                       q_of(x.z, invT, xm), q_of(x.w, invT, xm)};
        int base = iv * 4;
        #pragma unroll
        for (int k = 0; k < 4; k++) {
            u32 pb = __float_as_uint(qs[k]);
            if (pb == 0u) continue;
            int b = (int)(pb >> 18);
            if (b > bstar) {
                int v = base + k;
                float nz = noise_of(jbase + (u32)v);
                float sc = __fdividef(qs[k], nz);
                if (sc > bs || (sc == bs && v < bi)) { bs = sc; bi = v; }
            } else if (b == bstar) {
                int pos = atomicAdd(&sh_ng, 1);
                if (pos < 4096)
                    sortbuf[pos] = ((u64)pb << 32) | (u32)(~(u32)(base + k));
            }
        }
    }
    __syncthreads();
    if (bstar >= 0) {
        int n = sh_ng; if (n > 4096) n = 4096;
        int npad = 4; while (npad < n) npad <<= 1;
        for (int i = tid; i < npad; i += 1024) if (i >= n) sortbuf[i] = 0ULL;
        __syncthreads();
        for (int k = 2; k <= npad; k <<= 1) {
            for (int j = k >> 1; j > 0; j >>= 1) {
                for (int i = tid; i < npad; i += 1024) {
                    int pidx = i ^ j;
                    if (pidx > i) {
                        u64 a = sortbuf[i], b2 = sortbuf[pidx];
                        bool desc = ((i & k) == 0);
                        if (desc ? (a < b2) : (a > b2)) { sortbuf[i] = b2; sortbuf[pidx] = a; }
                    }
                }
                __syncthreads();
            }
        }
        double f0 = 0.0, f1 = 0.0, f2 = 0.0, f3 = 0.0;
        int t4 = tid * 4;
        if (t4 < npad) {
            f0 = (double)__uint_as_float((u32)(sortbuf[t4]     >> 32));
            f1 = (double)__uint_as_float((u32)(sortbuf[t4 + 1] >> 32));
            f2 = (double)__uint_as_float((u32)(sortbuf[t4 + 2] >> 32));
            f3 = (double)__uint_as_float((u32)(sortbuf[t4 + 3] >> 32));
        }
        double c0 = f0, c1 = c0 + f1, c2 = c1 + f2, c3 = c2 + f3;
        double incl2 = c3;
        for (int off = 1; off < 64; off <<= 1) {
            double u = __shfl_up(incl2, off);
            if (lane >= off) incl2 += u;
        }
        double excl2 = __shfl_up(incl2, 1);
        if (lane == 0) excl2 = 0.0;
        double wt = __shfl(incl2, 63);
        if (lane == 0) wtot[wid] = wt;
        __syncthreads();
        double cw2 = 0.0;
        for (int w = 0; w < wid; w++) cw2 += wtot[w];
        double cr = cw2 + excl2;
        if (t4 < npad) {
            bool m0 = (M + (cr + c0)) > cutZ;
            bool m1 = (M + (cr + c1)) > cutZ;
            bool m2 = (M + (cr + c2)) > cutZ;
            bool m3 = (M + (cr + c3)) > cutZ;
            int cand = m0 ? t4 : m1 ? (t4 + 1) : m2 ? (t4 + 2) : m3 ? (t4 + 3) : 0x7FFFFFFF;
            if (cand != 0x7FFFFFFF) atomicMin(&sh_jstar, cand);
        }
        __syncthreads();
        int jstar = sh_jstar; if (jstar > n) jstar = n;
        if (jstar == 0 && bstar == btop) jstar = 1;
        for (int i = tid; i < jstar; i += 1024) {
            u64 key = sortbuf[i];
            float qq = __uint_as_float((u32)(key >> 32));
            int v = (int)(~(u32)key);
            float nz = noise_of(jbase + (u32)v);
            float sc = __fdividef(qq, nz);
            if (sc > bs || (sc == bs && v < bi)) { bs = sc; bi = v; }
        }
    }
    for (int off = 32; off > 0; off >>= 1) {
        float ov = __shfl_down(bs, off);
        int   oi = __shfl_down(bi, off);
        if (ov > bs || (ov == bs && oi < bi)) { bs = ov; bi = oi; }
    }
    if (lane == 0) { wredf[wid] = bs; wredi[wid] = bi; }
    __syncthreads();
    if (tid == 0) {
        float v = wredf[0]; int i = wredi[0];
        for (int w = 1; w < 16; w++) {
            float ov = wredf[w]; int oi = wredi[w];
            if (ov > v || (ov == v && oi < i)) { v = ov; i = oi; }
        }
        out[row] = (Traw <= 1e-10f) ? gidx : i;
    }
}

extern "C" void kernel_launch(void* const* d_in, const int* in_sizes, int n_in,
                              void* d_out, int out_size, void* d_ws, size_t ws_size,
                              hipStream_t stream) {
    const float* logits = (const float*)d_in[0];
    const float* temps = (const float*)d_in[1];
    const float* topps = (const float*)d_in[2];
    int* out = (int*)d_out;
    (void)in_sizes; (void)n_in; (void)out_size;

    if (ws_size >= WS_TOTAL) {
        char* ws = (char*)d_ws;
        float* smax  = (float*)(ws + OFF_SMAX);
        int*   sarg  = (int*)(ws + OFF_SARG);
        u64*   wwin  = (u64*)(ws + OFF_WWIN);
        RowPar* par  = (RowPar*)(ws + OFF_PAR);
        int*   wcnt  = (int*)(ws + OFF_CNT);
        u64*   whist = (u64*)(ws + OFF_HIST);
        u64*   wlist = (u64*)(ws + OFF_LIST);
        k1_stats<<<BB * SLICES, 256, 0, stream>>>(logits, smax, sarg, whist, wcnt);
        k2_hist<<<BB * SLICES, 256, 0, stream>>>(logits, smax, temps, whist);
        k3_cut<<<BB, 1024, 0, stream>>>(whist, topps, par);
        k4_race<<<BB * SLICES, 256, 0, stream>>>(logits, smax, temps, par, wcnt, wlist, wwin);
        k5_final<<<BB, 1024, 0, stream>>>(smax, sarg, temps, topps, par, wcnt, wlist, wwin, out);
    } else {
        sampler_fallback<<<BB, 1024, 0, stream>>>(logits, temps, topps, out);
    }
}